// Round 2
// baseline (1286.050 us; speedup 1.0000x reference)
//
#include <hip/hip_runtime.h>

// ---------- bf16 helpers ----------
__device__ __forceinline__ float bf2f(unsigned short u) {
    return __uint_as_float(((unsigned)u) << 16);
}
__device__ __forceinline__ unsigned short f2bf(float f) {
    unsigned u = __float_as_uint(f);
    u += 0x7fffu + ((u >> 16) & 1u);   // round-to-nearest-even
    return (unsigned short)(u >> 16);
}
__device__ __forceinline__ void unpack8(uint4 u, float* f) {
    f[0] = __uint_as_float(u.x << 16); f[1] = __uint_as_float(u.x & 0xffff0000u);
    f[2] = __uint_as_float(u.y << 16); f[3] = __uint_as_float(u.y & 0xffff0000u);
    f[4] = __uint_as_float(u.z << 16); f[5] = __uint_as_float(u.z & 0xffff0000u);
    f[6] = __uint_as_float(u.w << 16); f[7] = __uint_as_float(u.w & 0xffff0000u);
}

struct Ptrs { const unsigned short* p[22]; };  // raw views; interpret per flag

// flag: 0 = inputs are bf16, 1 = inputs are fp32
__device__ __forceinline__ float loadEl(const unsigned short* p, long i, int f32) {
    return f32 ? ((const float*)p)[i] : bf2f(p[i]);
}

// fp32 weight buffer layout (element offsets)
constexpr int OFF_W1 = 0;       // [3 br][cin=3][k=9][cout=64]  = 5184
constexpr int OFF_B1 = 5184;    // [3][64]                      = 192
constexpr int OFF_W2 = 5376;    // [3][cin=64][9][cout=32]      = 55296
constexpr int OFF_B2 = 60672;   // [3][32]                      = 96
constexpr int OFF_W3 = 60768;   // [3][cin=32][9][cout=32]      = 27648
constexpr int OFF_B3 = 88416;   // [3][32]                      = 96
constexpr int OFF_WO = 88512;   // [cin=32][9][cout=3]          = 864
constexpr int OFF_BO = 89376;   // [3]
constexpr int OFF_PE = 89379;   // [225]

// ---------- input dtype detection ----------
// bf16 mode: even u16 entries are sane bf16 (|x|<8 -> exp<=0x81).
// fp32 mode: even u16 entries are low mantissa bits of floats -> ~uniform
// bit patterns; ~44% have exponent field >= 0x90.
__global__ void detect_kern(const unsigned short* x, int* flag) {
    int tid = threadIdx.x;
    int crazy = 0;
    for (int i = tid; i < 2048; i += 256) {
        unsigned short u = x[2 * i];
        int e = (u >> 7) & 0xFF;
        if (e >= 0x90) crazy++;
    }
    __shared__ int cnt;
    if (tid == 0) cnt = 0;
    __syncthreads();
    atomicAdd(&cnt, crazy);
    __syncthreads();
    if (tid == 0) *flag = (cnt > 32) ? 1 : 0;
}

// ---------- weight conversion / re-layout + canonical bf16 x ----------
__global__ __launch_bounds__(256) void prep_kern(Ptrs in, float* wb,
                                                 unsigned short* xc,
                                                 const int* flagp) {
    const int f32 = *flagp;
    int tid = blockIdx.x * 256 + threadIdx.x;
    int nth = gridDim.x * 256;
    for (int i = tid; i < 3 * 1728; i += nth) {               // w1: [64][3][9]
        int br = i / 1728, r = i % 1728;
        int cout = r / 27, cin = (r % 27) / 9, k = r % 9;
        wb[OFF_W1 + br * 1728 + (cin * 9 + k) * 64 + cout] = loadEl(in.p[1 + 6 * br], r, f32);
    }
    for (int i = tid; i < 3 * 18432; i += nth) {              // w2: [32][64][9]
        int br = i / 18432, r = i % 18432;
        int cout = r / 576, cin = (r % 576) / 9, k = r % 9;
        wb[OFF_W2 + br * 18432 + (cin * 9 + k) * 32 + cout] = loadEl(in.p[3 + 6 * br], r, f32);
    }
    for (int i = tid; i < 3 * 9216; i += nth) {               // w3: [32][32][9]
        int br = i / 9216, r = i % 9216;
        int cout = r / 288, cin = (r % 288) / 9, k = r % 9;
        wb[OFF_W3 + br * 9216 + (cin * 9 + k) * 32 + cout] = loadEl(in.p[5 + 6 * br], r, f32);
    }
    for (int i = tid; i < 864; i += nth) {                    // w_out: [3][32][9]
        int cout = i / 288, cin = (i % 288) / 9, k = i % 9;
        wb[OFF_WO + (cin * 9 + k) * 3 + cout] = loadEl(in.p[19], i, f32);
    }
    for (int i = tid; i < 192; i += nth) wb[OFF_B1 + i] = loadEl(in.p[2 + 6 * (i / 64)], i % 64, f32);
    for (int i = tid; i < 96;  i += nth) wb[OFF_B2 + i] = loadEl(in.p[4 + 6 * (i / 32)], i % 32, f32);
    for (int i = tid; i < 96;  i += nth) wb[OFF_B3 + i] = loadEl(in.p[6 + 6 * (i / 32)], i % 32, f32);
    for (int i = tid; i < 3;   i += nth) wb[OFF_BO + i] = loadEl(in.p[20], i, f32);
    for (int i = tid; i < 225; i += nth) wb[OFF_PE + i] = loadEl(in.p[21], i, f32);
    // canonical bf16 copy of x: 2*3*384*384 = 884736 elements
    for (int i = tid; i < 884736; i += nth) xc[i] = f2bf(loadEl(in.p[0], i, f32));
}

// ---------- generic direct 3x3 conv, NCHW bf16 -> NCHW bf16 ----------
template <int CIN, int COUT, bool RELU>
__global__ __launch_bounds__(256) void conv3x3_kern(
    const unsigned short* __restrict__ in, const float* __restrict__ wk,
    const float* __restrict__ bias, unsigned short* __restrict__ out) {
    __shared__ unsigned short sIn[CIN][18][18];
    const int b = blockIdx.z, h0 = blockIdx.y * 16, w0 = blockIdx.x * 16;
    const int tid = threadIdx.x;
    for (int idx = tid; idx < CIN * 324; idx += 256) {
        int c = idx / 324, r = idx % 324;
        int ih = r / 18, iw = r % 18;
        int gh = h0 + ih - 1, gw = w0 + iw - 1;
        unsigned short v = 0;
        if ((unsigned)gh < 384u && (unsigned)gw < 384u)
            v = in[((b * CIN + c) * 384 + gh) * 384 + gw];
        sIn[c][ih][iw] = v;
    }
    __syncthreads();
    const int tx = tid & 15, ty = tid >> 4;
    float acc[COUT];
#pragma unroll
    for (int co = 0; co < COUT; ++co) acc[co] = bias[co];
    for (int c = 0; c < CIN; ++c) {
        float v[9];
#pragma unroll
        for (int kh = 0; kh < 3; ++kh)
#pragma unroll
            for (int kw = 0; kw < 3; ++kw) v[kh * 3 + kw] = bf2f(sIn[c][ty + kh][tx + kw]);
#pragma unroll
        for (int k = 0; k < 9; ++k) {
            const float* wrow = wk + (c * 9 + k) * COUT;
#pragma unroll
            for (int co = 0; co < COUT; ++co) acc[co] = fmaf(v[k], wrow[co], acc[co]);
        }
    }
    const int h = h0 + ty, w = w0 + tx;
#pragma unroll
    for (int co = 0; co < COUT; ++co) {
        float o = acc[co];
        if (RELU) o = fmaxf(o, 0.f);
        out[((b * COUT + co) * 384 + h) * 384 + w] = f2bf(o);
    }
}

// ---------- conv3: 32->32, writes shifted+windowed QKV layout ----------
// qkv layout: [b][win(2304)][head(4)][tok(64)][d(8)] bf16
__global__ __launch_bounds__(256) void conv3x3_qkv(
    const unsigned short* __restrict__ in, const float* __restrict__ wk,
    const float* __restrict__ bias, unsigned short* __restrict__ qkv) {
    __shared__ unsigned short sIn[32][18][18];
    const int b = blockIdx.z, h0 = blockIdx.y * 16, w0 = blockIdx.x * 16;
    const int tid = threadIdx.x;
    for (int idx = tid; idx < 32 * 324; idx += 256) {
        int c = idx / 324, r = idx % 324;
        int ih = r / 18, iw = r % 18;
        int gh = h0 + ih - 1, gw = w0 + iw - 1;
        unsigned short v = 0;
        if ((unsigned)gh < 384u && (unsigned)gw < 384u)
            v = in[((b * 32 + c) * 384 + gh) * 384 + gw];
        sIn[c][ih][iw] = v;
    }
    __syncthreads();
    const int tx = tid & 15, ty = tid >> 4;
    float acc[32];
#pragma unroll
    for (int co = 0; co < 32; ++co) acc[co] = bias[co];
    for (int c = 0; c < 32; ++c) {
        float v[9];
#pragma unroll
        for (int kh = 0; kh < 3; ++kh)
#pragma unroll
            for (int kw = 0; kw < 3; ++kw) v[kh * 3 + kw] = bf2f(sIn[c][ty + kh][tx + kw]);
#pragma unroll
        for (int k = 0; k < 9; ++k) {
            const float* wrow = wk + (c * 9 + k) * 32;
#pragma unroll
            for (int co = 0; co < 32; ++co) acc[co] = fmaf(v[k], wrow[co], acc[co]);
        }
    }
    const int h = h0 + ty, w = w0 + tx;
    int sh = h - 4; if (sh < 0) sh += 384;   // cyclic shift by -4
    int sw = w - 4; if (sw < 0) sw += 384;
    const int wr = sh >> 3, wc = sw >> 3;
    const int win = wr * 48 + wc;
    const int tok = (sh & 7) * 8 + (sw & 7);
    const size_t base = (size_t)(b * 2304 + win) * 2048 + tok * 8;
#pragma unroll
    for (int co = 0; co < 32; ++co) {
        int head = co >> 3, d = co & 7;
        qkv[base + head * 512 + d] = f2bf(acc[co]);
    }
}

// ---------- windowed attention: one block per (win, b); wave = head ----------
// output att: shifted-space NCHW [b][32][384][384] bf16
__global__ __launch_bounds__(256) void attn_kern(
    const unsigned short* __restrict__ Q, const unsigned short* __restrict__ K,
    const unsigned short* __restrict__ V, const float* __restrict__ pos,
    unsigned short* __restrict__ att) {
    __shared__ float sK[4][64][8];
    __shared__ float sV[4][64][8];
    __shared__ float sP[225];
    const int win = blockIdx.x, b = blockIdx.y;
    const int tid = threadIdx.x;
    const int head = tid >> 6, lane = tid & 63;
    if (tid < 225) sP[tid] = pos[tid];
    const size_t base = ((size_t)(b * 2304 + win) * 4 + head) * 512;
    float q[8];
    unpack8(*reinterpret_cast<const uint4*>(Q + base + lane * 8), q);
    {
        float kr[8];
        unpack8(*reinterpret_cast<const uint4*>(K + base + lane * 8), kr);
#pragma unroll
        for (int d = 0; d < 8; ++d) sK[head][lane][d] = kr[d];
        float vr[8];
        unpack8(*reinterpret_cast<const uint4*>(V + base + lane * 8), vr);
#pragma unroll
        for (int d = 0; d < 8; ++d) sV[head][lane][d] = vr[d];
    }
    __syncthreads();
    const int ih = lane >> 3, iw = lane & 7;
    const int wr = win / 48, wc = win % 48;
    const bool mrow = (wr == 47), mcol = (wc == 47);
    const float SCALE = 0.35355339059327373f;  // 8^-0.5
    float s[64];
    float m = -1e30f;
#pragma unroll
    for (int j = 0; j < 64; ++j) {
        const float* kj = sK[head][j];
        float d0 = q[0] * kj[0];
#pragma unroll
        for (int d = 1; d < 8; ++d) d0 = fmaf(q[d], kj[d], d0);
        int jh = j >> 3, jw = j & 7;
        float sc = d0 * SCALE + sP[(jh - ih + 7) * 15 + (jw - iw + 7)];
        if (mrow && ((ih >= 4) != (jh >= 4))) sc = -1e30f;
        if (mcol && ((iw >= 4) != (jw >= 4))) sc = -1e30f;
        s[j] = sc;
        m = fmaxf(m, sc);
    }
    float sum = 0.f;
    float o[8] = {0.f, 0.f, 0.f, 0.f, 0.f, 0.f, 0.f, 0.f};
#pragma unroll
    for (int j = 0; j < 64; ++j) {
        float p = __expf(s[j] - m);
        sum += p;
        const float* vj = sV[head][j];
#pragma unroll
        for (int d = 0; d < 8; ++d) o[d] = fmaf(p, vj[d], o[d]);
    }
    const float inv = 1.0f / sum;
    const int sh = wr * 8 + ih, sw = wc * 8 + iw;
#pragma unroll
    for (int d = 0; d < 8; ++d)
        att[((b * 32 + head * 8 + d) * 384 + sh) * 384 + sw] = f2bf(o[d] * inv);
}

// ---------- out conv (shifted space) + inverse roll + residual ----------
__global__ __launch_bounds__(256) void outconv_kern(
    const unsigned short* __restrict__ att, const unsigned short* __restrict__ x_raw,
    const float* __restrict__ wk, const float* __restrict__ bias,
    void* __restrict__ outp, const int* __restrict__ flagp) {
    __shared__ unsigned short sIn[32][18][18];
    const int f32 = *flagp;
    const int b = blockIdx.z, h0 = blockIdx.y * 16, w0 = blockIdx.x * 16;
    const int tid = threadIdx.x;
    for (int idx = tid; idx < 32 * 324; idx += 256) {
        int c = idx / 324, r = idx % 324;
        int ih = r / 18, iw = r % 18;
        int gh = h0 + ih - 1, gw = w0 + iw - 1;
        unsigned short v = 0;
        if ((unsigned)gh < 384u && (unsigned)gw < 384u)
            v = att[((b * 32 + c) * 384 + gh) * 384 + gw];
        sIn[c][ih][iw] = v;
    }
    __syncthreads();
    const int tx = tid & 15, ty = tid >> 4;
    float acc[3] = {bias[0], bias[1], bias[2]};
    for (int c = 0; c < 32; ++c) {
        float v[9];
#pragma unroll
        for (int kh = 0; kh < 3; ++kh)
#pragma unroll
            for (int kw = 0; kw < 3; ++kw) v[kh * 3 + kw] = bf2f(sIn[c][ty + kh][tx + kw]);
#pragma unroll
        for (int k = 0; k < 9; ++k) {
            const float* wrow = wk + (c * 9 + k) * 3;
#pragma unroll
            for (int co = 0; co < 3; ++co) acc[co] = fmaf(v[k], wrow[co], acc[co]);
        }
    }
    const int sh = h0 + ty, sw = w0 + tx;
    int oh = sh + 4; if (oh >= 384) oh -= 384;  // inverse roll (+4)
    int ow = sw + 4; if (ow >= 384) ow -= 384;
#pragma unroll
    for (int co = 0; co < 3; ++co) {
        long idx = ((long)(b * 3 + co) * 384 + oh) * 384 + ow;
        float xv = loadEl(x_raw, idx, f32);      // exact-precision residual
        float o = acc[co] + xv;
        if (f32) ((float*)outp)[idx] = o;
        else ((unsigned short*)outp)[idx] = f2bf(o);
    }
}

extern "C" void kernel_launch(void* const* d_in, const int* in_sizes, int n_in,
                              void* d_out, int out_size, void* d_ws, size_t ws_size,
                              hipStream_t stream) {
    Ptrs P;
    for (int i = 0; i < 22; ++i) P.p[i] = (const unsigned short*)d_in[i];
    const unsigned short* x_raw = (const unsigned short*)d_in[0];

    char* ws = (char*)d_ws;
    float* wb = (float*)ws;                                    // fp32 weights, <384KB
    int* flag = (int*)(ws + 448 * 1024);
    size_t off = 512 * 1024;
    unsigned short* xc = (unsigned short*)(ws + off);          // canonical bf16 x
    off += (size_t)884736 * 2;
    off = (off + 1023) & ~(size_t)1023;
    unsigned short* h1 = (unsigned short*)(ws + off);          // [2][64][384][384] bf16
    off += (size_t)2 * 64 * 384 * 384 * 2;
    unsigned short* h2 = (unsigned short*)(ws + off);          // [2][32][384][384] bf16
    off += (size_t)2 * 32 * 384 * 384 * 2;
    unsigned short* qkv0 = (unsigned short*)(ws + off); off += (size_t)2 * 2304 * 2048 * 2;
    unsigned short* qkv1 = (unsigned short*)(ws + off); off += (size_t)2 * 2304 * 2048 * 2;
    unsigned short* qkv2 = (unsigned short*)(ws + off); off += (size_t)2 * 2304 * 2048 * 2;
    unsigned short* att = h1;  // alias: h1 dead after last conv2 read
    unsigned short* qkv[3] = {qkv0, qkv1, qkv2};

    detect_kern<<<dim3(1), dim3(256), 0, stream>>>(x_raw, flag);
    prep_kern<<<dim3(64), dim3(256), 0, stream>>>(P, wb, xc, flag);

    dim3 cgrid(24, 24, 2), cblk(256);
    for (int br = 0; br < 3; ++br) {
        conv3x3_kern<3, 64, true><<<cgrid, cblk, 0, stream>>>(
            xc, wb + OFF_W1 + br * 1728, wb + OFF_B1 + br * 64, h1);
        conv3x3_kern<64, 32, true><<<cgrid, cblk, 0, stream>>>(
            h1, wb + OFF_W2 + br * 18432, wb + OFF_B2 + br * 32, h2);
        conv3x3_qkv<<<cgrid, cblk, 0, stream>>>(
            h2, wb + OFF_W3 + br * 9216, wb + OFF_B3 + br * 32, qkv[br]);
    }
    attn_kern<<<dim3(2304, 2), dim3(256), 0, stream>>>(qkv0, qkv1, qkv2, wb + OFF_PE, att);
    outconv_kern<<<cgrid, cblk, 0, stream>>>(att, x_raw, wb + OFF_WO, wb + OFF_BO,
                                             d_out, flag);
}

// Round 3
// 395.356 us; speedup vs baseline: 3.2529x; 3.2529x over previous
//
#include <hip/hip_runtime.h>

typedef __attribute__((ext_vector_type(8))) short bf16x8;
typedef __attribute__((ext_vector_type(4))) float f32x4;

// ---------- bf16 helpers ----------
__device__ __forceinline__ float bf2f(unsigned short u) {
    return __uint_as_float(((unsigned)u) << 16);
}
__device__ __forceinline__ unsigned short f2bf(float f) {
    unsigned u = __float_as_uint(f);
    u += 0x7fffu + ((u >> 16) & 1u);   // round-to-nearest-even
    return (unsigned short)(u >> 16);
}
__device__ __forceinline__ void unpack8(uint4 u, float* f) {
    f[0] = __uint_as_float(u.x << 16); f[1] = __uint_as_float(u.x & 0xffff0000u);
    f[2] = __uint_as_float(u.y << 16); f[3] = __uint_as_float(u.y & 0xffff0000u);
    f[4] = __uint_as_float(u.z << 16); f[5] = __uint_as_float(u.z & 0xffff0000u);
    f[6] = __uint_as_float(u.w << 16); f[7] = __uint_as_float(u.w & 0xffff0000u);
}

struct Ptrs { const unsigned short* p[22]; };

// flag: 0 = inputs are bf16, 1 = inputs are fp32
__device__ __forceinline__ float loadEl(const unsigned short* p, long i, int f32) {
    return f32 ? ((const float*)p)[i] : bf2f(p[i]);
}

// fp32 scalar region (element offsets in wb)
constexpr int OFF_B1 = 5184;
constexpr int OFF_B2 = 60672;
constexpr int OFF_B3 = 88416;
constexpr int OFF_WO = 88512;   // [cin=32][k=9][cout=3]
constexpr int OFF_BO = 89376;
constexpr int OFF_PE = 89379;

// bf16 B-fragment tables (ushort offsets in wf)
constexpr int OFFW1 = 0;        // [br][nt=4][512]           = 3*2048
constexpr int OFFW2 = 6144;     // [br][36 frags][512]       = 3*18432
constexpr int OFFW3 = 61440;    // [br][18 frags][512]       = 3*9216

// ---------- input dtype detection ----------
__global__ void detect_kern(const unsigned short* x, int* flag) {
    int tid = threadIdx.x;
    int crazy = 0;
    for (int i = tid; i < 2048; i += 256) {
        unsigned short u = x[2 * i];
        int e = (u >> 7) & 0xFF;
        if (e >= 0x90) crazy++;
    }
    __shared__ int cnt;
    if (tid == 0) cnt = 0;
    __syncthreads();
    atomicAdd(&cnt, crazy);
    __syncthreads();
    if (tid == 0) *flag = (cnt > 32) ? 1 : 0;
}

// ---------- prep: biases/pos fp32, B-frag tables bf16, x -> NHWC(3 pad 4) ----------
__global__ __launch_bounds__(256) void prep_kern(Ptrs in, float* wb, unsigned short* wf,
                                                 unsigned short* xc, const int* flagp) {
    const int f32 = *flagp;
    int tid = blockIdx.x * 256 + threadIdx.x;
    int nth = gridDim.x * 256;
    for (int i = tid; i < 192; i += nth) wb[OFF_B1 + i] = loadEl(in.p[2 + 6 * (i / 64)], i % 64, f32);
    for (int i = tid; i < 96;  i += nth) wb[OFF_B2 + i] = loadEl(in.p[4 + 6 * (i / 32)], i % 32, f32);
    for (int i = tid; i < 96;  i += nth) wb[OFF_B3 + i] = loadEl(in.p[6 + 6 * (i / 32)], i % 32, f32);
    for (int i = tid; i < 864; i += nth) {
        int cout = i / 288, cin = (i % 288) / 9, k = i % 9;
        wb[OFF_WO + (cin * 9 + k) * 3 + cout] = loadEl(in.p[19], i, f32);
    }
    for (int i = tid; i < 3;   i += nth) wb[OFF_BO + i] = loadEl(in.p[20], i, f32);
    for (int i = tid; i < 225; i += nth) wb[OFF_PE + i] = loadEl(in.p[21], i, f32);
    // wf1: conv1 (K=27 pad 32, N=64): frag(nt) elem(lane,j): B[k][n]
    for (int i = tid; i < 3 * 2048; i += nth) {
        int br = i / 2048, r = i % 2048;
        int nt = r / 512, rr = r % 512, lane = rr >> 3, j = rr & 7;
        int k = ((lane >> 4) << 3) + j, n = nt * 16 + (lane & 15);
        float v = 0.f;
        if (k < 27) { int tap = k / 3, cin = k - tap * 3; v = loadEl(in.p[1 + 6 * br], n * 27 + cin * 9 + tap, f32); }
        wf[OFFW1 + i] = f2bf(v);
    }
    // wf2: conv2 (K=576=tap*64+cin, N=32): frag = s*2+nt, s in 0..17
    for (int i = tid; i < 3 * 18432; i += nth) {
        int br = i / 18432, r = i % 18432;
        int frag = r / 512, rr = r % 512, lane = rr >> 3, j = rr & 7;
        int s = frag >> 1, nt = frag & 1;
        int k = s * 32 + ((lane >> 4) << 3) + j, n = nt * 16 + (lane & 15);
        int cin = k & 63, tap = k >> 6;
        wf[OFFW2 + i] = f2bf(loadEl(in.p[3 + 6 * br], n * 576 + cin * 9 + tap, f32));
    }
    // wf3: conv3 (K=288=tap*32+cin, N=32): frag = s*2+nt, s in 0..8
    for (int i = tid; i < 3 * 9216; i += nth) {
        int br = i / 9216, r = i % 9216;
        int frag = r / 512, rr = r % 512, lane = rr >> 3, j = rr & 7;
        int s = frag >> 1, nt = frag & 1;
        int k = s * 32 + ((lane >> 4) << 3) + j, n = nt * 16 + (lane & 15);
        int cin = k & 31, tap = k >> 5;
        wf[OFFW3 + i] = f2bf(loadEl(in.p[5 + 6 * br], n * 288 + cin * 9 + tap, f32));
    }
    // xc: NHWC with ch padded 3->4
    for (int i = tid; i < 2 * 147456 * 4; i += nth) {
        int c = i & 3, p = i >> 2;
        int b = p / 147456, hw = p % 147456;
        float v = (c < 3) ? loadEl(in.p[0], (long)(b * 3 + c) * 147456 + hw, f32) : 0.f;
        xc[i] = f2bf(v);
    }
}

// ---------- conv1 MFMA: 3->64, NHWC out ----------
__global__ __launch_bounds__(256) void conv1_mfma(
    const unsigned short* __restrict__ xc, const unsigned short* __restrict__ wf,
    const float* __restrict__ bias, unsigned short* __restrict__ out) {
    __shared__ __align__(16) unsigned short sIn[3][66][4];
    const int b = blockIdx.z, h = blockIdx.y, w0 = blockIdx.x * 64;
    const int tid = threadIdx.x;
    for (int idx = tid; idx < 198; idx += 256) {
        int col = idx % 66, kh = idx / 66;
        int gh = h + kh - 1, gw = w0 + col - 1;
        uint2 v = make_uint2(0, 0);
        if ((unsigned)gh < 384u && (unsigned)gw < 384u)
            v = *(const uint2*)(xc + ((size_t)(b * 147456 + gh * 384 + gw) << 2));
        *(uint2*)(&sIn[kh][col][0]) = v;
    }
    __syncthreads();
    const int lane = tid & 63, wave = tid >> 6;
    const int mcol = lane & 15, q = lane >> 4;
    bf16x8 a;
#pragma unroll
    for (int j = 0; j < 8; ++j) {
        int k = q * 8 + j;
        int tap = k / 3, cin = k - tap * 3;
        if (tap > 8) { tap = 8; cin = 3; }          // clamp into pad lane
        int kh = tap / 3, kw = tap - kh * 3;
        short val = (short)sIn[kh][wave * 16 + mcol + kw][cin];
        a[j] = (k < 27) ? val : (short)0;
    }
    const size_t pbase = (size_t)(b * 147456 + h * 384 + w0 + wave * 16 + q * 4);
#pragma unroll
    for (int nt = 0; nt < 4; ++nt) {
        float bn = bias[nt * 16 + mcol];
        f32x4 acc = {bn, bn, bn, bn};
        bf16x8 bf = *(const bf16x8*)(wf + nt * 512 + lane * 8);
        acc = __builtin_amdgcn_mfma_f32_16x16x32_bf16(a, bf, acc, 0, 0, 0);
        size_t base = pbase * 64 + nt * 16 + mcol;
#pragma unroll
        for (int r = 0; r < 4; ++r)
            out[base + (size_t)r * 64] = f2bf(fmaxf(acc[r], 0.f));
    }
}

// ---------- conv2 MFMA: 64->32, NHWC in/out ----------
__global__ __launch_bounds__(256) void conv2_mfma(
    const unsigned short* __restrict__ in, const unsigned short* __restrict__ wf,
    const float* __restrict__ bias, unsigned short* __restrict__ out) {
    __shared__ __align__(16) unsigned short sIn[3][66][72];   // +8 ch pad
    const int b = blockIdx.z, h = blockIdx.y, w0 = blockIdx.x * 64;
    const int tid = threadIdx.x;
    for (int idx = tid; idx < 1584; idx += 256) {
        int seg = idx & 7, col = (idx >> 3) % 66, kh = (idx >> 3) / 66;
        int gh = h + kh - 1, gw = w0 + col - 1;
        uint4 v = make_uint4(0, 0, 0, 0);
        if ((unsigned)gh < 384u && (unsigned)gw < 384u)
            v = *(const uint4*)(in + ((size_t)(b * 147456 + gh * 384 + gw) << 6) + seg * 8);
        *(uint4*)(&sIn[kh][col][seg * 8]) = v;
    }
    __syncthreads();
    const int lane = tid & 63, wave = tid >> 6;
    const int mcol = lane & 15, q = lane >> 4;
    f32x4 acc0, acc1;
    {
        float b0 = bias[mcol], b1 = bias[16 + mcol];
        acc0 = f32x4{b0, b0, b0, b0}; acc1 = f32x4{b1, b1, b1, b1};
    }
    for (int kh = 0; kh < 3; ++kh) {
        const unsigned short* sbase = &sIn[kh][wave * 16 + mcol][0];
        const unsigned short* wbase = wf + kh * 6 * 1024 + lane * 8;
#pragma unroll
        for (int u = 0; u < 6; ++u) {            // s = kh*6+u; tap=s/2, half-channel = s&1
            const int kw = u >> 1, ch0 = (u & 1) * 32;
            bf16x8 a  = *(const bf16x8*)(sbase + kw * 72 + ch0 + q * 8);
            bf16x8 b0 = *(const bf16x8*)(wbase + u * 1024);
            bf16x8 b1 = *(const bf16x8*)(wbase + u * 1024 + 512);
            acc0 = __builtin_amdgcn_mfma_f32_16x16x32_bf16(a, b0, acc0, 0, 0, 0);
            acc1 = __builtin_amdgcn_mfma_f32_16x16x32_bf16(a, b1, acc1, 0, 0, 0);
        }
    }
    size_t base = (size_t)(b * 147456 + h * 384 + w0 + wave * 16 + q * 4) * 32 + mcol;
#pragma unroll
    for (int r = 0; r < 4; ++r) {
        out[base + (size_t)r * 32]      = f2bf(fmaxf(acc0[r], 0.f));
        out[base + (size_t)r * 32 + 16] = f2bf(fmaxf(acc1[r], 0.f));
    }
}

// ---------- conv3 MFMA: 32->32, epilogue scatters to shifted windowed QKV ----------
// qkv layout: [b][win(2304)][head(4)][tok(64)][d(8)] bf16
__global__ __launch_bounds__(256) void conv3_mfma(
    const unsigned short* __restrict__ in, const unsigned short* __restrict__ wf,
    const float* __restrict__ bias, unsigned short* __restrict__ qkv) {
    __shared__ __align__(16) unsigned short sIn[3][66][40];   // +8 ch pad
    const int b = blockIdx.z, h = blockIdx.y, w0 = blockIdx.x * 64;
    const int tid = threadIdx.x;
    for (int idx = tid; idx < 792; idx += 256) {
        int seg = idx & 3, col = (idx >> 2) % 66, kh = (idx >> 2) / 66;
        int gh = h + kh - 1, gw = w0 + col - 1;
        uint4 v = make_uint4(0, 0, 0, 0);
        if ((unsigned)gh < 384u && (unsigned)gw < 384u)
            v = *(const uint4*)(in + ((size_t)(b * 147456 + gh * 384 + gw) << 5) + seg * 8);
        *(uint4*)(&sIn[kh][col][seg * 8]) = v;
    }
    __syncthreads();
    const int lane = tid & 63, wave = tid >> 6;
    const int mcol = lane & 15, q = lane >> 4;
    f32x4 acc0, acc1;
    {
        float b0 = bias[mcol], b1 = bias[16 + mcol];
        acc0 = f32x4{b0, b0, b0, b0}; acc1 = f32x4{b1, b1, b1, b1};
    }
    for (int kh = 0; kh < 3; ++kh) {
        const unsigned short* sbase = &sIn[kh][wave * 16 + mcol][0];
        const unsigned short* wbase = wf + kh * 3 * 1024 + lane * 8;
#pragma unroll
        for (int u = 0; u < 3; ++u) {            // s = kh*3+u = tap, kw = u
            bf16x8 a  = *(const bf16x8*)(sbase + u * 40 + q * 8);
            bf16x8 b0 = *(const bf16x8*)(wbase + u * 1024);
            bf16x8 b1 = *(const bf16x8*)(wbase + u * 1024 + 512);
            acc0 = __builtin_amdgcn_mfma_f32_16x16x32_bf16(a, b0, acc0, 0, 0, 0);
            acc1 = __builtin_amdgcn_mfma_f32_16x16x32_bf16(a, b1, acc1, 0, 0, 0);
        }
    }
    const int n0 = mcol, n1 = 16 + mcol;
    int sh = h - 4; if (sh < 0) sh += 384;
#pragma unroll
    for (int r = 0; r < 4; ++r) {
        int w = w0 + wave * 16 + q * 4 + r;
        int sw = w - 4; if (sw < 0) sw += 384;
        int win = (sh >> 3) * 48 + (sw >> 3);
        int tok = (sh & 7) * 8 + (sw & 7);
        size_t base = ((size_t)(b * 2304 + win) * 4) * 512 + tok * 8;
        qkv[base + (size_t)(n0 >> 3) * 512 + (n0 & 7)] = f2bf(acc0[r]);
        qkv[base + (size_t)(n1 >> 3) * 512 + (n1 & 7)] = f2bf(acc1[r]);
    }
}

// ---------- windowed attention (unchanged from round 2) ----------
__global__ __launch_bounds__(256) void attn_kern(
    const unsigned short* __restrict__ Q, const unsigned short* __restrict__ K,
    const unsigned short* __restrict__ V, const float* __restrict__ pos,
    unsigned short* __restrict__ att) {
    __shared__ float sK[4][64][8];
    __shared__ float sV[4][64][8];
    __shared__ float sP[225];
    const int win = blockIdx.x, b = blockIdx.y;
    const int tid = threadIdx.x;
    const int head = tid >> 6, lane = tid & 63;
    if (tid < 225) sP[tid] = pos[tid];
    const size_t base = ((size_t)(b * 2304 + win) * 4 + head) * 512;
    float q[8];
    unpack8(*reinterpret_cast<const uint4*>(Q + base + lane * 8), q);
    {
        float kr[8];
        unpack8(*reinterpret_cast<const uint4*>(K + base + lane * 8), kr);
#pragma unroll
        for (int d = 0; d < 8; ++d) sK[head][lane][d] = kr[d];
        float vr[8];
        unpack8(*reinterpret_cast<const uint4*>(V + base + lane * 8), vr);
#pragma unroll
        for (int d = 0; d < 8; ++d) sV[head][lane][d] = vr[d];
    }
    __syncthreads();
    const int ih = lane >> 3, iw = lane & 7;
    const int wr = win / 48, wc = win % 48;
    const bool mrow = (wr == 47), mcol2 = (wc == 47);
    const float SCALE = 0.35355339059327373f;
    float s[64];
    float m = -1e30f;
#pragma unroll
    for (int j = 0; j < 64; ++j) {
        const float* kj = sK[head][j];
        float d0 = q[0] * kj[0];
#pragma unroll
        for (int d = 1; d < 8; ++d) d0 = fmaf(q[d], kj[d], d0);
        int jh = j >> 3, jw = j & 7;
        float sc = d0 * SCALE + sP[(jh - ih + 7) * 15 + (jw - iw + 7)];
        if (mrow && ((ih >= 4) != (jh >= 4))) sc = -1e30f;
        if (mcol2 && ((iw >= 4) != (jw >= 4))) sc = -1e30f;
        s[j] = sc;
        m = fmaxf(m, sc);
    }
    float sum = 0.f;
    float o[8] = {0.f, 0.f, 0.f, 0.f, 0.f, 0.f, 0.f, 0.f};
#pragma unroll
    for (int j = 0; j < 64; ++j) {
        float p = __expf(s[j] - m);
        sum += p;
        const float* vj = sV[head][j];
#pragma unroll
        for (int d = 0; d < 8; ++d) o[d] = fmaf(p, vj[d], o[d]);
    }
    const float inv = 1.0f / sum;
    const int sh = wr * 8 + ih, sw = wc * 8 + iw;
#pragma unroll
    for (int d = 0; d < 8; ++d)
        att[((b * 32 + head * 8 + d) * 384 + sh) * 384 + sw] = f2bf(o[d] * inv);
}

// ---------- out conv (shifted space) + inverse roll + residual ----------
__global__ __launch_bounds__(256) void outconv_kern(
    const unsigned short* __restrict__ att, const unsigned short* __restrict__ x_raw,
    const float* __restrict__ wk, const float* __restrict__ bias,
    void* __restrict__ outp, const int* __restrict__ flagp) {
    __shared__ unsigned short sIn[32][18][18];
    const int f32 = *flagp;
    const int b = blockIdx.z, h0 = blockIdx.y * 16, w0 = blockIdx.x * 16;
    const int tid = threadIdx.x;
    for (int idx = tid; idx < 32 * 324; idx += 256) {
        int c = idx / 324, r = idx % 324;
        int ih = r / 18, iw = r % 18;
        int gh = h0 + ih - 1, gw = w0 + iw - 1;
        unsigned short v = 0;
        if ((unsigned)gh < 384u && (unsigned)gw < 384u)
            v = att[((b * 32 + c) * 384 + gh) * 384 + gw];
        sIn[c][ih][iw] = v;
    }
    __syncthreads();
    const int tx = tid & 15, ty = tid >> 4;
    float acc[3] = {bias[0], bias[1], bias[2]};
    for (int c = 0; c < 32; ++c) {
        float v[9];
#pragma unroll
        for (int kh = 0; kh < 3; ++kh)
#pragma unroll
            for (int kw = 0; kw < 3; ++kw) v[kh * 3 + kw] = bf2f(sIn[c][ty + kh][tx + kw]);
#pragma unroll
        for (int k = 0; k < 9; ++k) {
            const float* wrow = wk + (c * 9 + k) * 3;
#pragma unroll
            for (int co = 0; co < 3; ++co) acc[co] = fmaf(v[k], wrow[co], acc[co]);
        }
    }
    const int sh = h0 + ty, sw = w0 + tx;
    int oh = sh + 4; if (oh >= 384) oh -= 384;
    int ow = sw + 4; if (ow >= 384) ow -= 384;
#pragma unroll
    for (int co = 0; co < 3; ++co) {
        long idx = ((long)(b * 3 + co) * 384 + oh) * 384 + ow;
        float xv = loadEl(x_raw, idx, f32);
        float o = acc[co] + xv;
        if (f32) ((float*)outp)[idx] = o;
        else ((unsigned short*)outp)[idx] = f2bf(o);
    }
}

extern "C" void kernel_launch(void* const* d_in, const int* in_sizes, int n_in,
                              void* d_out, int out_size, void* d_ws, size_t ws_size,
                              hipStream_t stream) {
    Ptrs P;
    for (int i = 0; i < 22; ++i) P.p[i] = (const unsigned short*)d_in[i];
    const unsigned short* x_raw = (const unsigned short*)d_in[0];

    char* ws = (char*)d_ws;
    float* wb = (float*)ws;                                   // fp32 scalars
    int* flag = (int*)(ws + 448 * 1024);
    unsigned short* wf = (unsigned short*)(ws + 512 * 1024);  // B-frag tables (182 KB)
    unsigned short* xc = (unsigned short*)(ws + 1024 * 1024); // NHWC3(pad4), 2.36 MB
    size_t off = 3584 * 1024;                                 // 3.5 MB
    unsigned short* h1 = (unsigned short*)(ws + off);         // NHWC64, 37.75 MB (per-branch reuse)
    unsigned short* qkv2 = h1;                                // alias: h1 dead before conv3(br2) writes
    unsigned short* att = (unsigned short*)(ws + off + 18874368); // alias upper half of h1
    off += 37748736;
    unsigned short* h2 = (unsigned short*)(ws + off); off += 18874368;   // NHWC32 per-branch
    unsigned short* qkv0 = (unsigned short*)(ws + off); off += 18874368;
    unsigned short* qkv1 = (unsigned short*)(ws + off); off += 18874368;
    unsigned short* qkv[3] = {qkv0, qkv1, qkv2};

    detect_kern<<<dim3(1), dim3(256), 0, stream>>>(x_raw, flag);
    prep_kern<<<dim3(256), dim3(256), 0, stream>>>(P, wb, wf, xc, flag);

    dim3 cg(6, 384, 2), cb(256);
    for (int br = 0; br < 3; ++br) {
        conv1_mfma<<<cg, cb, 0, stream>>>(xc, wf + OFFW1 + br * 2048,
                                          wb + OFF_B1 + br * 64, h1);
        conv2_mfma<<<cg, cb, 0, stream>>>(h1, wf + OFFW2 + br * 18432,
                                          wb + OFF_B2 + br * 32, h2);
        conv3_mfma<<<cg, cb, 0, stream>>>(h2, wf + OFFW3 + br * 9216,
                                          wb + OFF_B3 + br * 32, qkv[br]);
    }
    attn_kern<<<dim3(2304, 2), dim3(256), 0, stream>>>(qkv0, qkv1, qkv2, wb + OFF_PE, att);
    outconv_kern<<<dim3(24, 24, 2), dim3(256), 0, stream>>>(att, x_raw, wb + OFF_WO,
                                                            wb + OFF_BO, d_out, flag);
}

// Round 4
// 366.511 us; speedup vs baseline: 3.5089x; 1.0787x over previous
//
#include <hip/hip_runtime.h>

typedef __attribute__((ext_vector_type(8))) short bf16x8;
typedef __attribute__((ext_vector_type(4))) float f32x4;

// ---------- bf16 helpers ----------
__device__ __forceinline__ float bf2f(unsigned short u) {
    return __uint_as_float(((unsigned)u) << 16);
}
__device__ __forceinline__ unsigned short f2bf(float f) {
    unsigned u = __float_as_uint(f);
    u += 0x7fffu + ((u >> 16) & 1u);   // round-to-nearest-even
    return (unsigned short)(u >> 16);
}
__device__ __forceinline__ void unpack8(uint4 u, float* f) {
    f[0] = __uint_as_float(u.x << 16); f[1] = __uint_as_float(u.x & 0xffff0000u);
    f[2] = __uint_as_float(u.y << 16); f[3] = __uint_as_float(u.y & 0xffff0000u);
    f[4] = __uint_as_float(u.z << 16); f[5] = __uint_as_float(u.z & 0xffff0000u);
    f[6] = __uint_as_float(u.w << 16); f[7] = __uint_as_float(u.w & 0xffff0000u);
}

struct Ptrs { const unsigned short* p[22]; };

__device__ __forceinline__ float loadEl(const unsigned short* p, long i, int f32) {
    return f32 ? ((const float*)p)[i] : bf2f(p[i]);
}

// fp32 scalar region (element offsets in wb)
constexpr int OFF_B1 = 5184;
constexpr int OFF_B2 = 60672;
constexpr int OFF_B3 = 88416;
constexpr int OFF_BO = 89376;
constexpr int OFF_BT = 90112;   // biasT[4 cls][64 j][64 i] fp32 = 16384

// bf16 B-fragment tables (ushort offsets in wf)
constexpr int OFFW1 = 0;        // [br][nt=4][512]
constexpr int OFFW2 = 6144;     // [br][36 frags][512]
constexpr int OFFW3 = 61440;    // [br][18 frags][512]
constexpr int OFFWO = 89088;    // [9 frags][512]

// ---------- input dtype detection ----------
__global__ void detect_kern(const unsigned short* x, int* flag) {
    int tid = threadIdx.x;
    int crazy = 0;
    for (int i = tid; i < 2048; i += 256) {
        unsigned short u = x[2 * i];
        int e = (u >> 7) & 0xFF;
        if (e >= 0x90) crazy++;
    }
    __shared__ int cnt;
    if (tid == 0) cnt = 0;
    __syncthreads();
    atomicAdd(&cnt, crazy);
    __syncthreads();
    if (tid == 0) *flag = (cnt > 32) ? 1 : 0;
}

// ---------- prep ----------
__global__ __launch_bounds__(256) void prep_kern(Ptrs in, float* wb, unsigned short* wf,
                                                 unsigned short* xc, const int* flagp) {
    const int f32 = *flagp;
    int tid = blockIdx.x * 256 + threadIdx.x;
    int nth = gridDim.x * 256;
    for (int i = tid; i < 192; i += nth) wb[OFF_B1 + i] = loadEl(in.p[2 + 6 * (i / 64)], i % 64, f32);
    for (int i = tid; i < 96;  i += nth) wb[OFF_B2 + i] = loadEl(in.p[4 + 6 * (i / 32)], i % 32, f32);
    for (int i = tid; i < 96;  i += nth) wb[OFF_B3 + i] = loadEl(in.p[6 + 6 * (i / 32)], i % 32, f32);
    for (int i = tid; i < 3;   i += nth) wb[OFF_BO + i] = loadEl(in.p[20], i, f32);
    // biasT: pos-bias + baked shift masks, [cls][j][i] (i = query token)
    for (int i = tid; i < 16384; i += nth) {
        int cls = i >> 12, rem = i & 4095, j = rem >> 6, qi = rem & 63;
        int ih = qi >> 3, iw = qi & 7, jh = j >> 3, jw = j & 7;
        float v = loadEl(in.p[21], (jh - ih + 7) * 15 + (jw - iw + 7), f32);
        if ((cls & 1) && ((ih >= 4) != (jh >= 4))) v = -1e30f;
        if ((cls & 2) && ((iw >= 4) != (jw >= 4))) v = -1e30f;
        wb[OFF_BT + i] = v;
    }
    // wf1: conv1 (K=27 pad 32, N=64)
    for (int i = tid; i < 3 * 2048; i += nth) {
        int br = i / 2048, r = i % 2048;
        int nt = r / 512, rr = r % 512, lane = rr >> 3, j = rr & 7;
        int k = ((lane >> 4) << 3) + j, n = nt * 16 + (lane & 15);
        float v = 0.f;
        if (k < 27) { int tap = k / 3, cin = k - tap * 3; v = loadEl(in.p[1 + 6 * br], n * 27 + cin * 9 + tap, f32); }
        wf[OFFW1 + i] = f2bf(v);
    }
    // wf2: conv2 (K=576=tap*64+cin, N=32)
    for (int i = tid; i < 3 * 18432; i += nth) {
        int br = i / 18432, r = i % 18432;
        int frag = r / 512, rr = r % 512, lane = rr >> 3, j = rr & 7;
        int s = frag >> 1, nt = frag & 1;
        int k = s * 32 + ((lane >> 4) << 3) + j, n = nt * 16 + (lane & 15);
        int cin = k & 63, tap = k >> 6;
        wf[OFFW2 + i] = f2bf(loadEl(in.p[3 + 6 * br], n * 576 + cin * 9 + tap, f32));
    }
    // wf3: conv3 (K=288=tap*32+cin, N=32)
    for (int i = tid; i < 3 * 9216; i += nth) {
        int br = i / 9216, r = i % 9216;
        int frag = r / 512, rr = r % 512, lane = rr >> 3, j = rr & 7;
        int s = frag >> 1, nt = frag & 1;
        int k = s * 32 + ((lane >> 4) << 3) + j, n = nt * 16 + (lane & 15);
        int cin = k & 31, tap = k >> 5;
        wf[OFFW3 + i] = f2bf(loadEl(in.p[5 + 6 * br], n * 288 + cin * 9 + tap, f32));
    }
    // wfO: outconv (K=288, N=16 with 3 valid)
    for (int i = tid; i < 4608; i += nth) {
        int frag = i / 512, rr = i % 512, lane = rr >> 3, j = rr & 7;
        int k = frag * 32 + ((lane >> 4) << 3) + j, n = lane & 15;
        float v = (n < 3) ? loadEl(in.p[19], n * 288 + (k & 31) * 9 + (k >> 5), f32) : 0.f;
        wf[OFFWO + i] = f2bf(v);
    }
    // xc: NHWC with ch padded 3->4
    for (int i = tid; i < 2 * 147456 * 4; i += nth) {
        int c = i & 3, p = i >> 2;
        int b = p / 147456, hw = p % 147456;
        float v = (c < 3) ? loadEl(in.p[0], (long)(b * 3 + c) * 147456 + hw, f32) : 0.f;
        xc[i] = f2bf(v);
    }
}

// ---------- conv1 MFMA: 3->64, NHWC out, 4 rows/block ----------
__global__ __launch_bounds__(256) void conv1_mfma(
    const unsigned short* __restrict__ xc, const unsigned short* __restrict__ wf,
    const float* __restrict__ bias, unsigned short* __restrict__ out) {
    __shared__ __align__(16) unsigned short sIn[6][66][4];
    const int b = blockIdx.z, h0 = blockIdx.y * 4, w0 = blockIdx.x * 64;
    const int tid = threadIdx.x;
    for (int idx = tid; idx < 396; idx += 256) {
        int col = idx % 66, kr = idx / 66;
        int gh = h0 + kr - 1, gw = w0 + col - 1;
        uint2 v = make_uint2(0, 0);
        if ((unsigned)gh < 384u && (unsigned)gw < 384u)
            v = *(const uint2*)(xc + ((size_t)(b * 147456 + gh * 384 + gw) << 2));
        *(uint2*)(&sIn[kr][col][0]) = v;
    }
    __syncthreads();
    const int lane = tid & 63, wave = tid >> 6;
    const int mcol = lane & 15, q = lane >> 4;
    bf16x8 a[4];
#pragma unroll
    for (int hr = 0; hr < 4; ++hr)
#pragma unroll
        for (int j = 0; j < 8; ++j) {
            int k = q * 8 + j;
            int tap = k / 3, cin = k - tap * 3;
            if (tap > 8) { tap = 8; cin = 3; }
            int kh = tap / 3, kw = tap - kh * 3;
            short val = (short)sIn[hr + kh][wave * 16 + mcol + kw][cin];
            a[hr][j] = (k < 27) ? val : (short)0;
        }
#pragma unroll
    for (int nt = 0; nt < 4; ++nt) {
        float bn = bias[nt * 16 + mcol];
        bf16x8 bf = *(const bf16x8*)(wf + nt * 512 + lane * 8);
#pragma unroll
        for (int hr = 0; hr < 4; ++hr) {
            f32x4 acc = {bn, bn, bn, bn};
            acc = __builtin_amdgcn_mfma_f32_16x16x32_bf16(a[hr], bf, acc, 0, 0, 0);
            size_t base = (size_t)(b * 147456 + (h0 + hr) * 384 + w0 + wave * 16 + q * 4) * 64 + nt * 16 + mcol;
#pragma unroll
            for (int r = 0; r < 4; ++r)
                out[base + (size_t)r * 64] = f2bf(fmaxf(acc[r], 0.f));
        }
    }
}

// ---------- conv2 MFMA: 64->32, NHWC, 4 rows/block ----------
__global__ __launch_bounds__(256) void conv2_mfma(
    const unsigned short* __restrict__ in, const unsigned short* __restrict__ wf,
    const float* __restrict__ bias, unsigned short* __restrict__ out) {
    __shared__ __align__(16) unsigned short sIn[6][66][72];
    const int b = blockIdx.z, h0 = blockIdx.y * 4, w0 = blockIdx.x * 64;
    const int tid = threadIdx.x;
    for (int idx = tid; idx < 3168; idx += 256) {
        int seg = idx & 7, t = idx >> 3, col = t % 66, kr = t / 66;
        int gh = h0 + kr - 1, gw = w0 + col - 1;
        uint4 v = make_uint4(0, 0, 0, 0);
        if ((unsigned)gh < 384u && (unsigned)gw < 384u)
            v = *(const uint4*)(in + ((size_t)(b * 147456 + gh * 384 + gw) << 6) + seg * 8);
        *(uint4*)(&sIn[kr][col][seg * 8]) = v;
    }
    __syncthreads();
    const int lane = tid & 63, wave = tid >> 6;
    const int mcol = lane & 15, q = lane >> 4;
    f32x4 acc[2][4];
    {
        float b0 = bias[mcol], b1 = bias[16 + mcol];
#pragma unroll
        for (int hr = 0; hr < 4; ++hr) {
            acc[0][hr] = f32x4{b0, b0, b0, b0};
            acc[1][hr] = f32x4{b1, b1, b1, b1};
        }
    }
    for (int kh = 0; kh < 3; ++kh) {
        const unsigned short* wbase = wf + kh * 6 * 1024 + lane * 8;
#pragma unroll
        for (int u = 0; u < 6; ++u) {
            const int kw = u >> 1, ch0 = (u & 1) * 32;
            bf16x8 b0 = *(const bf16x8*)(wbase + u * 1024);
            bf16x8 b1 = *(const bf16x8*)(wbase + u * 1024 + 512);
#pragma unroll
            for (int hr = 0; hr < 4; ++hr) {
                bf16x8 a = *(const bf16x8*)(&sIn[kh + hr][wave * 16 + mcol + kw][ch0 + q * 8]);
                acc[0][hr] = __builtin_amdgcn_mfma_f32_16x16x32_bf16(a, b0, acc[0][hr], 0, 0, 0);
                acc[1][hr] = __builtin_amdgcn_mfma_f32_16x16x32_bf16(a, b1, acc[1][hr], 0, 0, 0);
            }
        }
    }
#pragma unroll
    for (int hr = 0; hr < 4; ++hr) {
        size_t base = (size_t)(b * 147456 + (h0 + hr) * 384 + w0 + wave * 16 + q * 4) * 32 + mcol;
#pragma unroll
        for (int r = 0; r < 4; ++r) {
            out[base + (size_t)r * 32]      = f2bf(fmaxf(acc[0][hr][r], 0.f));
            out[base + (size_t)r * 32 + 16] = f2bf(fmaxf(acc[1][hr][r], 0.f));
        }
    }
}

// ---------- conv3 MFMA: 32->32, QKV scatter epilogue, 4 rows/block ----------
__global__ __launch_bounds__(256) void conv3_mfma(
    const unsigned short* __restrict__ in, const unsigned short* __restrict__ wf,
    const float* __restrict__ bias, unsigned short* __restrict__ qkv) {
    __shared__ __align__(16) unsigned short sIn[6][66][40];
    const int b = blockIdx.z, h0 = blockIdx.y * 4, w0 = blockIdx.x * 64;
    const int tid = threadIdx.x;
    for (int idx = tid; idx < 1584; idx += 256) {
        int seg = idx & 3, t = idx >> 2, col = t % 66, kr = t / 66;
        int gh = h0 + kr - 1, gw = w0 + col - 1;
        uint4 v = make_uint4(0, 0, 0, 0);
        if ((unsigned)gh < 384u && (unsigned)gw < 384u)
            v = *(const uint4*)(in + ((size_t)(b * 147456 + gh * 384 + gw) << 5) + seg * 8);
        *(uint4*)(&sIn[kr][col][seg * 8]) = v;
    }
    __syncthreads();
    const int lane = tid & 63, wave = tid >> 6;
    const int mcol = lane & 15, q = lane >> 4;
    f32x4 acc[2][4];
    {
        float b0 = bias[mcol], b1 = bias[16 + mcol];
#pragma unroll
        for (int hr = 0; hr < 4; ++hr) {
            acc[0][hr] = f32x4{b0, b0, b0, b0};
            acc[1][hr] = f32x4{b1, b1, b1, b1};
        }
    }
    for (int kh = 0; kh < 3; ++kh) {
        const unsigned short* wbase = wf + kh * 3 * 1024 + lane * 8;
#pragma unroll
        for (int u = 0; u < 3; ++u) {
            bf16x8 b0 = *(const bf16x8*)(wbase + u * 1024);
            bf16x8 b1 = *(const bf16x8*)(wbase + u * 1024 + 512);
#pragma unroll
            for (int hr = 0; hr < 4; ++hr) {
                bf16x8 a = *(const bf16x8*)(&sIn[kh + hr][wave * 16 + mcol + u][q * 8]);
                acc[0][hr] = __builtin_amdgcn_mfma_f32_16x16x32_bf16(a, b0, acc[0][hr], 0, 0, 0);
                acc[1][hr] = __builtin_amdgcn_mfma_f32_16x16x32_bf16(a, b1, acc[1][hr], 0, 0, 0);
            }
        }
    }
    const int n0 = mcol, n1 = 16 + mcol;
#pragma unroll
    for (int hr = 0; hr < 4; ++hr) {
        int sh = h0 + hr - 4; if (sh < 0) sh += 384;
#pragma unroll
        for (int r = 0; r < 4; ++r) {
            int w = w0 + wave * 16 + q * 4 + r;
            int sw = w - 4; if (sw < 0) sw += 384;
            int win = (sh >> 3) * 48 + (sw >> 3);
            int tok = (sh & 7) * 8 + (sw & 7);
            size_t base = ((size_t)(b * 2304 + win) * 4) * 512 + tok * 8;
            qkv[base + (size_t)(n0 >> 3) * 512 + (n0 & 7)] = f2bf(acc[0][hr][r]);
            qkv[base + (size_t)(n1 >> 3) * 512 + (n1 & 7)] = f2bf(acc[1][hr][r]);
        }
    }
}

// ---------- windowed attention: online softmax, class-baked bias tables ----------
// output att: shifted-space NHWC32 [b][384*384][32] bf16
__global__ __launch_bounds__(256) void attn_kern(
    const unsigned short* __restrict__ Q, const unsigned short* __restrict__ K,
    const unsigned short* __restrict__ V, const float* __restrict__ biasT,
    unsigned short* __restrict__ att) {
    __shared__ float sK[4][64][8];
    __shared__ float sV[4][64][8];
    __shared__ float sB[4096];
    const int win = blockIdx.x, b = blockIdx.y;
    const int tid = threadIdx.x;
    const int head = tid >> 6, lane = tid & 63;
    const int wr = win / 48, wc = win % 48;
    const int cls = (wr == 47 ? 1 : 0) + (wc == 47 ? 2 : 0);
    {
        const float4* gB = (const float4*)(biasT + cls * 4096);
        float4* sB4 = (float4*)sB;
        for (int i = tid; i < 1024; i += 256) sB4[i] = gB[i];
    }
    const size_t base = ((size_t)(b * 2304 + win) * 4 + head) * 512;
    float q[8];
    unpack8(*reinterpret_cast<const uint4*>(Q + base + lane * 8), q);
    {
        float kr[8], vr[8];
        unpack8(*reinterpret_cast<const uint4*>(K + base + lane * 8), kr);
        unpack8(*reinterpret_cast<const uint4*>(V + base + lane * 8), vr);
#pragma unroll
        for (int d = 0; d < 8; ++d) { sK[head][lane][d] = kr[d]; sV[head][lane][d] = vr[d]; }
    }
    __syncthreads();
    const float SCALE = 0.35355339059327373f;  // 8^-0.5
    float m = -3e30f, sum = 0.f;
    float o[8] = {0.f, 0.f, 0.f, 0.f, 0.f, 0.f, 0.f, 0.f};
#pragma unroll 4
    for (int j = 0; j < 64; ++j) {
        const float* kj = sK[head][j];
        float d0 = q[0] * kj[0];
#pragma unroll
        for (int d = 1; d < 8; ++d) d0 = fmaf(q[d], kj[d], d0);
        float sc = d0 * SCALE + sB[j * 64 + lane];
        if (sc > m) {
            float r = __expf(m - sc);
            sum *= r;
#pragma unroll
            for (int d = 0; d < 8; ++d) o[d] *= r;
            m = sc;
        }
        float p = __expf(sc - m);
        sum += p;
        const float* vj = sV[head][j];
#pragma unroll
        for (int d = 0; d < 8; ++d) o[d] = fmaf(p, vj[d], o[d]);
    }
    const float inv = 1.0f / sum;
    const int ih = lane >> 3, iw = lane & 7;
    const int px = (wr * 8 + ih) * 384 + wc * 8 + iw;
    unsigned short us[8];
#pragma unroll
    for (int d = 0; d < 8; ++d) us[d] = f2bf(o[d] * inv);
    uint4 pk;
    pk.x = (unsigned)us[0] | ((unsigned)us[1] << 16);
    pk.y = (unsigned)us[2] | ((unsigned)us[3] << 16);
    pk.z = (unsigned)us[4] | ((unsigned)us[5] << 16);
    pk.w = (unsigned)us[6] | ((unsigned)us[7] << 16);
    *(uint4*)(att + (((size_t)(b * 147456 + px)) << 5) + head * 8) = pk;
}

// ---------- out conv MFMA (shifted space, NHWC32 in) + inverse roll + residual ----------
__global__ __launch_bounds__(256) void outconv_mfma(
    const unsigned short* __restrict__ att, const unsigned short* __restrict__ x_raw,
    const unsigned short* __restrict__ wf, const float* __restrict__ wb,
    void* __restrict__ outp, const int* __restrict__ flagp) {
    __shared__ __align__(16) unsigned short sIn[6][66][40];
    const int f32 = *flagp;
    const int b = blockIdx.z, h0 = blockIdx.y * 4, w0 = blockIdx.x * 64;
    const int tid = threadIdx.x;
    for (int idx = tid; idx < 1584; idx += 256) {
        int seg = idx & 3, t = idx >> 2, col = t % 66, kr = t / 66;
        int gh = h0 + kr - 1, gw = w0 + col - 1;
        uint4 v = make_uint4(0, 0, 0, 0);
        if ((unsigned)gh < 384u && (unsigned)gw < 384u)
            v = *(const uint4*)(att + ((size_t)(b * 147456 + gh * 384 + gw) << 5) + seg * 8);
        *(uint4*)(&sIn[kr][col][seg * 8]) = v;
    }
    __syncthreads();
    const int lane = tid & 63, wave = tid >> 6;
    const int mcol = lane & 15, q = lane >> 4;
    float bn = (mcol < 3) ? wb[OFF_BO + mcol] : 0.f;
    f32x4 acc[4];
#pragma unroll
    for (int hr = 0; hr < 4; ++hr) acc[hr] = f32x4{bn, bn, bn, bn};
    for (int kh = 0; kh < 3; ++kh) {
        const unsigned short* wbase = wf + kh * 3 * 512 + lane * 8;
#pragma unroll
        for (int u = 0; u < 3; ++u) {
            bf16x8 bf = *(const bf16x8*)(wbase + u * 512);
#pragma unroll
            for (int hr = 0; hr < 4; ++hr) {
                bf16x8 a = *(const bf16x8*)(&sIn[kh + hr][wave * 16 + mcol + u][q * 8]);
                acc[hr] = __builtin_amdgcn_mfma_f32_16x16x32_bf16(a, bf, acc[hr], 0, 0, 0);
            }
        }
    }
    if (mcol < 3) {
#pragma unroll
        for (int hr = 0; hr < 4; ++hr) {
            int oh = h0 + hr + 4; if (oh >= 384) oh -= 384;
#pragma unroll
            for (int r = 0; r < 4; ++r) {
                int w = w0 + wave * 16 + q * 4 + r;
                int ow = w + 4; if (ow >= 384) ow -= 384;
                long idx = (long)(b * 3 + mcol) * 147456 + oh * 384 + ow;
                float xv = loadEl(x_raw, idx, f32);
                float o = acc[hr][r] + xv;
                if (f32) ((float*)outp)[idx] = o;
                else ((unsigned short*)outp)[idx] = f2bf(o);
            }
        }
    }
}

extern "C" void kernel_launch(void* const* d_in, const int* in_sizes, int n_in,
                              void* d_out, int out_size, void* d_ws, size_t ws_size,
                              hipStream_t stream) {
    Ptrs P;
    for (int i = 0; i < 22; ++i) P.p[i] = (const unsigned short*)d_in[i];
    const unsigned short* x_raw = (const unsigned short*)d_in[0];

    char* ws = (char*)d_ws;
    float* wb = (float*)ws;                                   // fp32 scalars + biasT (<448KB)
    int* flag = (int*)(ws + 448 * 1024);
    unsigned short* wf = (unsigned short*)(ws + 512 * 1024);  // B-frag tables (<512KB)
    unsigned short* xc = (unsigned short*)(ws + 1024 * 1024); // NHWC3(pad4)
    size_t off = 3584 * 1024;
    unsigned short* h1 = (unsigned short*)(ws + off);         // NHWC64, 37.75MB (reused/branch)
    unsigned short* qkv2 = h1;                                // alias (h1 dead when written)
    unsigned short* att = (unsigned short*)(ws + off + 18874368); // NHWC32 shifted, alias h1 hi
    off += 37748736;
    unsigned short* h2 = (unsigned short*)(ws + off); off += 18874368;
    unsigned short* qkv0 = (unsigned short*)(ws + off); off += 18874368;
    unsigned short* qkv1 = (unsigned short*)(ws + off); off += 18874368;
    unsigned short* qkv[3] = {qkv0, qkv1, qkv2};

    detect_kern<<<dim3(1), dim3(256), 0, stream>>>(x_raw, flag);
    prep_kern<<<dim3(256), dim3(256), 0, stream>>>(P, wb, wf, xc, flag);

    dim3 cg(6, 96, 2), cb(256);
    for (int br = 0; br < 3; ++br) {
        conv1_mfma<<<cg, cb, 0, stream>>>(xc, wf + OFFW1 + br * 2048,
                                          wb + OFF_B1 + br * 64, h1);
        conv2_mfma<<<cg, cb, 0, stream>>>(h1, wf + OFFW2 + br * 18432,
                                          wb + OFF_B2 + br * 32, h2);
        conv3_mfma<<<cg, cb, 0, stream>>>(h2, wf + OFFW3 + br * 9216,
                                          wb + OFF_B3 + br * 32, qkv[br]);
    }
    attn_kern<<<dim3(2304, 2), dim3(256), 0, stream>>>(qkv0, qkv1, qkv2, wb + OFF_BT, att);
    outconv_mfma<<<cg, cb, 0, stream>>>(att, x_raw, wf + OFFWO, wb, d_out, flag);
}

// Round 5
// 347.102 us; speedup vs baseline: 3.7051x; 1.0559x over previous
//
#include <hip/hip_runtime.h>

typedef __attribute__((ext_vector_type(8))) short bf16x8;
typedef __attribute__((ext_vector_type(4))) float f32x4;

// ---------- bf16 helpers ----------
__device__ __forceinline__ float bf2f(unsigned short u) {
    return __uint_as_float(((unsigned)u) << 16);
}
__device__ __forceinline__ unsigned short f2bf(float f) {
    unsigned u = __float_as_uint(f);
    u += 0x7fffu + ((u >> 16) & 1u);   // round-to-nearest-even
    return (unsigned short)(u >> 16);
}
__device__ __forceinline__ void unpack8(uint4 u, float* f) {
    f[0] = __uint_as_float(u.x << 16); f[1] = __uint_as_float(u.x & 0xffff0000u);
    f[2] = __uint_as_float(u.y << 16); f[3] = __uint_as_float(u.y & 0xffff0000u);
    f[4] = __uint_as_float(u.z << 16); f[5] = __uint_as_float(u.z & 0xffff0000u);
    f[6] = __uint_as_float(u.w << 16); f[7] = __uint_as_float(u.w & 0xffff0000u);
}

struct Ptrs { const unsigned short* p[22]; };

__device__ __forceinline__ float loadEl(const unsigned short* p, long i, int f32) {
    return f32 ? ((const float*)p)[i] : bf2f(p[i]);
}

// fp32 scalar region (element offsets in wb)
constexpr int OFF_B1 = 5184;
constexpr int OFF_B2 = 60672;
constexpr int OFF_B3 = 88416;
constexpr int OFF_BO = 89376;

// bf16 tables (ushort offsets in wf)
constexpr int OFFW1 = 0;        // [br][nt=4][512]
constexpr int OFFW2 = 6144;     // [br][36 frags][512]
constexpr int OFFW3 = 61440;    // [br][18 frags][512]
constexpr int OFFWO = 89088;    // [9 frags][512]
constexpr int OFFBT = 93696;    // biasT bf16 [4 cls][64 j][64 i] = 16384

// ---------- input dtype detection ----------
__global__ void detect_kern(const unsigned short* x, int* flag) {
    int tid = threadIdx.x;
    int crazy = 0;
    for (int i = tid; i < 2048; i += 256) {
        unsigned short u = x[2 * i];
        int e = (u >> 7) & 0xFF;
        if (e >= 0x90) crazy++;
    }
    __shared__ int cnt;
    if (tid == 0) cnt = 0;
    __syncthreads();
    atomicAdd(&cnt, crazy);
    __syncthreads();
    if (tid == 0) *flag = (cnt > 32) ? 1 : 0;
}

// ---------- prep ----------
__global__ __launch_bounds__(256) void prep_kern(Ptrs in, float* wb, unsigned short* wf,
                                                 unsigned short* xc, const int* flagp) {
    const int f32 = *flagp;
    int tid = blockIdx.x * 256 + threadIdx.x;
    int nth = gridDim.x * 256;
    for (int i = tid; i < 192; i += nth) wb[OFF_B1 + i] = loadEl(in.p[2 + 6 * (i / 64)], i % 64, f32);
    for (int i = tid; i < 96;  i += nth) wb[OFF_B2 + i] = loadEl(in.p[4 + 6 * (i / 32)], i % 32, f32);
    for (int i = tid; i < 96;  i += nth) wb[OFF_B3 + i] = loadEl(in.p[6 + 6 * (i / 32)], i % 32, f32);
    for (int i = tid; i < 3;   i += nth) wb[OFF_BO + i] = loadEl(in.p[20], i, f32);
    // biasT bf16: pos-bias + baked shift masks, [cls][j][i] (i = query token)
    for (int i = tid; i < 16384; i += nth) {
        int cls = i >> 12, rem = i & 4095, j = rem >> 6, qi = rem & 63;
        int ih = qi >> 3, iw = qi & 7, jh = j >> 3, jw = j & 7;
        float v = loadEl(in.p[21], (jh - ih + 7) * 15 + (jw - iw + 7), f32);
        if ((cls & 1) && ((ih >= 4) != (jh >= 4))) v = -1e30f;
        if ((cls & 2) && ((iw >= 4) != (jw >= 4))) v = -1e30f;
        wf[OFFBT + i] = f2bf(v);
    }
    // wf1: conv1 (K=27 pad 32, N=64)
    for (int i = tid; i < 3 * 2048; i += nth) {
        int br = i / 2048, r = i % 2048;
        int nt = r / 512, rr = r % 512, lane = rr >> 3, j = rr & 7;
        int k = ((lane >> 4) << 3) + j, n = nt * 16 + (lane & 15);
        float v = 0.f;
        if (k < 27) { int tap = k / 3, cin = k - tap * 3; v = loadEl(in.p[1 + 6 * br], n * 27 + cin * 9 + tap, f32); }
        wf[OFFW1 + i] = f2bf(v);
    }
    // wf2: conv2 (K=576=tap*64+cin, N=32)
    for (int i = tid; i < 3 * 18432; i += nth) {
        int br = i / 18432, r = i % 18432;
        int frag = r / 512, rr = r % 512, lane = rr >> 3, j = rr & 7;
        int s = frag >> 1, nt = frag & 1;
        int k = s * 32 + ((lane >> 4) << 3) + j, n = nt * 16 + (lane & 15);
        int cin = k & 63, tap = k >> 6;
        wf[OFFW2 + i] = f2bf(loadEl(in.p[3 + 6 * br], n * 576 + cin * 9 + tap, f32));
    }
    // wf3: conv3 (K=288=tap*32+cin, N=32)
    for (int i = tid; i < 3 * 9216; i += nth) {
        int br = i / 9216, r = i % 9216;
        int frag = r / 512, rr = r % 512, lane = rr >> 3, j = rr & 7;
        int s = frag >> 1, nt = frag & 1;
        int k = s * 32 + ((lane >> 4) << 3) + j, n = nt * 16 + (lane & 15);
        int cin = k & 31, tap = k >> 5;
        wf[OFFW3 + i] = f2bf(loadEl(in.p[5 + 6 * br], n * 288 + cin * 9 + tap, f32));
    }
    // wfO: outconv (K=288, N=16 with 3 valid)
    for (int i = tid; i < 4608; i += nth) {
        int frag = i / 512, rr = i % 512, lane = rr >> 3, j = rr & 7;
        int k = frag * 32 + ((lane >> 4) << 3) + j, n = lane & 15;
        float v = (n < 3) ? loadEl(in.p[19], n * 288 + (k & 31) * 9 + (k >> 5), f32) : 0.f;
        wf[OFFWO + i] = f2bf(v);
    }
    // xc: NHWC with ch padded 3->4
    for (int i = tid; i < 2 * 147456 * 4; i += nth) {
        int c = i & 3, p = i >> 2;
        int b = p / 147456, hw = p % 147456;
        float v = (c < 3) ? loadEl(in.p[0], (long)(b * 3 + c) * 147456 + hw, f32) : 0.f;
        xc[i] = f2bf(v);
    }
}

// ---------- conv1 MFMA: 3->64, NHWC out, 4 rows/block ----------
__global__ __launch_bounds__(256) void conv1_mfma(
    const unsigned short* __restrict__ xc, const unsigned short* __restrict__ wf,
    const float* __restrict__ bias, unsigned short* __restrict__ out) {
    __shared__ __align__(16) unsigned short sIn[6][66][4];
    const int b = blockIdx.z, h0 = blockIdx.y * 4, w0 = blockIdx.x * 64;
    const int tid = threadIdx.x;
    for (int idx = tid; idx < 396; idx += 256) {
        int col = idx % 66, kr = idx / 66;
        int gh = h0 + kr - 1, gw = w0 + col - 1;
        uint2 v = make_uint2(0, 0);
        if ((unsigned)gh < 384u && (unsigned)gw < 384u)
            v = *(const uint2*)(xc + ((size_t)(b * 147456 + gh * 384 + gw) << 2));
        *(uint2*)(&sIn[kr][col][0]) = v;
    }
    __syncthreads();
    const int lane = tid & 63, wave = tid >> 6;
    const int mcol = lane & 15, q = lane >> 4;
    bf16x8 a[4];
#pragma unroll
    for (int hr = 0; hr < 4; ++hr)
#pragma unroll
        for (int j = 0; j < 8; ++j) {
            int k = q * 8 + j;
            int tap = k / 3, cin = k - tap * 3;
            if (tap > 8) { tap = 8; cin = 3; }
            int kh = tap / 3, kw = tap - kh * 3;
            short val = (short)sIn[hr + kh][wave * 16 + mcol + kw][cin];
            a[hr][j] = (k < 27) ? val : (short)0;
        }
#pragma unroll
    for (int nt = 0; nt < 4; ++nt) {
        float bn = bias[nt * 16 + mcol];
        bf16x8 bf = *(const bf16x8*)(wf + nt * 512 + lane * 8);
#pragma unroll
        for (int hr = 0; hr < 4; ++hr) {
            f32x4 acc = {bn, bn, bn, bn};
            acc = __builtin_amdgcn_mfma_f32_16x16x32_bf16(a[hr], bf, acc, 0, 0, 0);
            size_t base = (size_t)(b * 147456 + (h0 + hr) * 384 + w0 + wave * 16 + q * 4) * 64 + nt * 16 + mcol;
#pragma unroll
            for (int r = 0; r < 4; ++r)
                out[base + (size_t)r * 64] = f2bf(fmaxf(acc[r], 0.f));
        }
    }
}

// ---------- conv2 MFMA: 64->32, NHWC, 2 rows/block (38KB LDS -> 4 blocks/CU) ----------
__global__ __launch_bounds__(256) void conv2_mfma(
    const unsigned short* __restrict__ in, const unsigned short* __restrict__ wf,
    const float* __restrict__ bias, unsigned short* __restrict__ out) {
    __shared__ __align__(16) unsigned short sIn[4][66][72];
    const int b = blockIdx.z, h0 = blockIdx.y * 2, w0 = blockIdx.x * 64;
    const int tid = threadIdx.x;
    for (int idx = tid; idx < 2112; idx += 256) {
        int seg = idx & 7, t = idx >> 3, col = t % 66, kr = t / 66;
        int gh = h0 + kr - 1, gw = w0 + col - 1;
        uint4 v = make_uint4(0, 0, 0, 0);
        if ((unsigned)gh < 384u && (unsigned)gw < 384u)
            v = *(const uint4*)(in + ((size_t)(b * 147456 + gh * 384 + gw) << 6) + seg * 8);
        *(uint4*)(&sIn[kr][col][seg * 8]) = v;
    }
    __syncthreads();
    const int lane = tid & 63, wave = tid >> 6;
    const int mcol = lane & 15, q = lane >> 4;
    f32x4 acc[2][2];
    {
        float b0 = bias[mcol], b1 = bias[16 + mcol];
#pragma unroll
        for (int hr = 0; hr < 2; ++hr) {
            acc[0][hr] = f32x4{b0, b0, b0, b0};
            acc[1][hr] = f32x4{b1, b1, b1, b1};
        }
    }
    for (int kh = 0; kh < 3; ++kh) {
        const unsigned short* wbase = wf + kh * 6 * 1024 + lane * 8;
#pragma unroll
        for (int u = 0; u < 6; ++u) {
            const int kw = u >> 1, ch0 = (u & 1) * 32;
            bf16x8 b0 = *(const bf16x8*)(wbase + u * 1024);
            bf16x8 b1 = *(const bf16x8*)(wbase + u * 1024 + 512);
#pragma unroll
            for (int hr = 0; hr < 2; ++hr) {
                bf16x8 a = *(const bf16x8*)(&sIn[kh + hr][wave * 16 + mcol + kw][ch0 + q * 8]);
                acc[0][hr] = __builtin_amdgcn_mfma_f32_16x16x32_bf16(a, b0, acc[0][hr], 0, 0, 0);
                acc[1][hr] = __builtin_amdgcn_mfma_f32_16x16x32_bf16(a, b1, acc[1][hr], 0, 0, 0);
            }
        }
    }
#pragma unroll
    for (int hr = 0; hr < 2; ++hr) {
        size_t base = (size_t)(b * 147456 + (h0 + hr) * 384 + w0 + wave * 16 + q * 4) * 32 + mcol;
#pragma unroll
        for (int r = 0; r < 4; ++r) {
            out[base + (size_t)r * 32]      = f2bf(fmaxf(acc[0][hr][r], 0.f));
            out[base + (size_t)r * 32 + 16] = f2bf(fmaxf(acc[1][hr][r], 0.f));
        }
    }
}

// ---------- conv3 MFMA: 32->32, QKV scatter epilogue, 4 rows/block ----------
__global__ __launch_bounds__(256) void conv3_mfma(
    const unsigned short* __restrict__ in, const unsigned short* __restrict__ wf,
    const float* __restrict__ bias, unsigned short* __restrict__ qkv) {
    __shared__ __align__(16) unsigned short sIn[6][66][40];
    const int b = blockIdx.z, h0 = blockIdx.y * 4, w0 = blockIdx.x * 64;
    const int tid = threadIdx.x;
    for (int idx = tid; idx < 1584; idx += 256) {
        int seg = idx & 3, t = idx >> 2, col = t % 66, kr = t / 66;
        int gh = h0 + kr - 1, gw = w0 + col - 1;
        uint4 v = make_uint4(0, 0, 0, 0);
        if ((unsigned)gh < 384u && (unsigned)gw < 384u)
            v = *(const uint4*)(in + ((size_t)(b * 147456 + gh * 384 + gw) << 5) + seg * 8);
        *(uint4*)(&sIn[kr][col][seg * 8]) = v;
    }
    __syncthreads();
    const int lane = tid & 63, wave = tid >> 6;
    const int mcol = lane & 15, q = lane >> 4;
    f32x4 acc[2][4];
    {
        float b0 = bias[mcol], b1 = bias[16 + mcol];
#pragma unroll
        for (int hr = 0; hr < 4; ++hr) {
            acc[0][hr] = f32x4{b0, b0, b0, b0};
            acc[1][hr] = f32x4{b1, b1, b1, b1};
        }
    }
    for (int kh = 0; kh < 3; ++kh) {
        const unsigned short* wbase = wf + kh * 3 * 1024 + lane * 8;
#pragma unroll
        for (int u = 0; u < 3; ++u) {
            bf16x8 b0 = *(const bf16x8*)(wbase + u * 1024);
            bf16x8 b1 = *(const bf16x8*)(wbase + u * 1024 + 512);
#pragma unroll
            for (int hr = 0; hr < 4; ++hr) {
                bf16x8 a = *(const bf16x8*)(&sIn[kh + hr][wave * 16 + mcol + u][q * 8]);
                acc[0][hr] = __builtin_amdgcn_mfma_f32_16x16x32_bf16(a, b0, acc[0][hr], 0, 0, 0);
                acc[1][hr] = __builtin_amdgcn_mfma_f32_16x16x32_bf16(a, b1, acc[1][hr], 0, 0, 0);
            }
        }
    }
    const int n0 = mcol, n1 = 16 + mcol;
#pragma unroll
    for (int hr = 0; hr < 4; ++hr) {
        int sh = h0 + hr - 4; if (sh < 0) sh += 384;
#pragma unroll
        for (int r = 0; r < 4; ++r) {
            int w = w0 + wave * 16 + q * 4 + r;
            int sw = w - 4; if (sw < 0) sw += 384;
            int win = (sh >> 3) * 48 + (sw >> 3);
            int tok = (sh & 7) * 8 + (sw & 7);
            size_t base = ((size_t)(b * 2304 + win) * 4) * 512 + tok * 8;
            qkv[base + (size_t)(n0 >> 3) * 512 + (n0 & 7)] = f2bf(acc[0][hr][r]);
            qkv[base + (size_t)(n1 >> 3) * 512 + (n1 & 7)] = f2bf(acc[1][hr][r]);
        }
    }
}

// ---------- windowed attention: branch-free no-max softmax ----------
// output att: shifted-space NHWC32 [b][384*384][32] bf16
__global__ __launch_bounds__(256) void attn_kern(
    const unsigned short* __restrict__ Q, const unsigned short* __restrict__ K,
    const unsigned short* __restrict__ V, const unsigned short* __restrict__ biasTb,
    unsigned short* __restrict__ att) {
    __shared__ float sK[4][64][8];
    __shared__ float sV[4][64][8];
    __shared__ unsigned short sB[4096];
    const int win = blockIdx.x, b = blockIdx.y;
    const int tid = threadIdx.x;
    const int head = tid >> 6, lane = tid & 63;
    const int wr = win / 48, wc = win % 48;
    const int cls = (wr == 47 ? 1 : 0) + (wc == 47 ? 2 : 0);
    {
        const uint4* gB = (const uint4*)(biasTb + cls * 4096);
        uint4* s4 = (uint4*)sB;
        s4[tid] = gB[tid];
        if (tid < 256) s4[tid + 256] = gB[tid + 256];
    }
    const size_t base = ((size_t)(b * 2304 + win) * 4 + head) * 512;
    float q[8];
    unpack8(*reinterpret_cast<const uint4*>(Q + base + lane * 8), q);
    {
        float kr[8], vr[8];
        unpack8(*reinterpret_cast<const uint4*>(K + base + lane * 8), kr);
        unpack8(*reinterpret_cast<const uint4*>(V + base + lane * 8), vr);
#pragma unroll
        for (int d = 0; d < 8; ++d) { sK[head][lane][d] = kr[d]; sV[head][lane][d] = vr[d]; }
    }
    __syncthreads();
    const float SCALE = 0.35355339059327373f;  // 8^-0.5
    float sum = 0.f;
    float o[8] = {0.f, 0.f, 0.f, 0.f, 0.f, 0.f, 0.f, 0.f};
#pragma unroll 8
    for (int j = 0; j < 64; ++j) {
        const float* kj = sK[head][j];
        float d0 = q[0] * kj[0];
#pragma unroll
        for (int d = 1; d < 8; ++d) d0 = fmaf(q[d], kj[d], d0);
        float sc = fmaf(d0, SCALE, bf2f(sB[j * 64 + lane]));
        float p = __expf(fminf(sc, 60.f));   // masked: bias -1e30 -> exp underflows to 0
        sum += p;
        const float* vj = sV[head][j];
#pragma unroll
        for (int d = 0; d < 8; ++d) o[d] = fmaf(p, vj[d], o[d]);
    }
    const float inv = 1.0f / sum;
    const int ih = lane >> 3, iw = lane & 7;
    const int px = (wr * 8 + ih) * 384 + wc * 8 + iw;
    unsigned short us[8];
#pragma unroll
    for (int d = 0; d < 8; ++d) us[d] = f2bf(o[d] * inv);
    uint4 pk;
    pk.x = (unsigned)us[0] | ((unsigned)us[1] << 16);
    pk.y = (unsigned)us[2] | ((unsigned)us[3] << 16);
    pk.z = (unsigned)us[4] | ((unsigned)us[5] << 16);
    pk.w = (unsigned)us[6] | ((unsigned)us[7] << 16);
    *(uint4*)(att + (((size_t)(b * 147456 + px)) << 5) + head * 8) = pk;
}

// ---------- out conv MFMA (shifted space, NHWC32 in) + inverse roll + residual ----------
__global__ __launch_bounds__(256) void outconv_mfma(
    const unsigned short* __restrict__ att, const unsigned short* __restrict__ x_raw,
    const unsigned short* __restrict__ wf, const float* __restrict__ wb,
    void* __restrict__ outp, const int* __restrict__ flagp) {
    __shared__ __align__(16) unsigned short sIn[6][66][40];
    const int f32 = *flagp;
    const int b = blockIdx.z, h0 = blockIdx.y * 4, w0 = blockIdx.x * 64;
    const int tid = threadIdx.x;
    for (int idx = tid; idx < 1584; idx += 256) {
        int seg = idx & 3, t = idx >> 2, col = t % 66, kr = t / 66;
        int gh = h0 + kr - 1, gw = w0 + col - 1;
        uint4 v = make_uint4(0, 0, 0, 0);
        if ((unsigned)gh < 384u && (unsigned)gw < 384u)
            v = *(const uint4*)(att + ((size_t)(b * 147456 + gh * 384 + gw) << 5) + seg * 8);
        *(uint4*)(&sIn[kr][col][seg * 8]) = v;
    }
    __syncthreads();
    const int lane = tid & 63, wave = tid >> 6;
    const int mcol = lane & 15, q = lane >> 4;
    float bn = (mcol < 3) ? wb[OFF_BO + mcol] : 0.f;
    f32x4 acc[4];
#pragma unroll
    for (int hr = 0; hr < 4; ++hr) acc[hr] = f32x4{bn, bn, bn, bn};
    for (int kh = 0; kh < 3; ++kh) {
        const unsigned short* wbase = wf + kh * 3 * 512 + lane * 8;
#pragma unroll
        for (int u = 0; u < 3; ++u) {
            bf16x8 bf = *(const bf16x8*)(wbase + u * 512);
#pragma unroll
            for (int hr = 0; hr < 4; ++hr) {
                bf16x8 a = *(const bf16x8*)(&sIn[kh + hr][wave * 16 + mcol + u][q * 8]);
                acc[hr] = __builtin_amdgcn_mfma_f32_16x16x32_bf16(a, bf, acc[hr], 0, 0, 0);
            }
        }
    }
    if (mcol < 3) {
#pragma unroll
        for (int hr = 0; hr < 4; ++hr) {
            int oh = h0 + hr + 4; if (oh >= 384) oh -= 384;
#pragma unroll
            for (int r = 0; r < 4; ++r) {
                int w = w0 + wave * 16 + q * 4 + r;
                int ow = w + 4; if (ow >= 384) ow -= 384;
                long idx = (long)(b * 3 + mcol) * 147456 + oh * 384 + ow;
                float xv = loadEl(x_raw, idx, f32);
                float o = acc[hr][r] + xv;
                if (f32) ((float*)outp)[idx] = o;
                else ((unsigned short*)outp)[idx] = f2bf(o);
            }
        }
    }
}

extern "C" void kernel_launch(void* const* d_in, const int* in_sizes, int n_in,
                              void* d_out, int out_size, void* d_ws, size_t ws_size,
                              hipStream_t stream) {
    Ptrs P;
    for (int i = 0; i < 22; ++i) P.p[i] = (const unsigned short*)d_in[i];
    const unsigned short* x_raw = (const unsigned short*)d_in[0];

    char* ws = (char*)d_ws;
    float* wb = (float*)ws;                                   // fp32 scalars (<448KB)
    int* flag = (int*)(ws + 448 * 1024);
    unsigned short* wf = (unsigned short*)(ws + 512 * 1024);  // bf16 tables (<512KB)
    unsigned short* xc = (unsigned short*)(ws + 1024 * 1024); // NHWC3(pad4)
    size_t off = 3584 * 1024;
    unsigned short* h1 = (unsigned short*)(ws + off);         // NHWC64, 37.75MB (reused/branch)
    unsigned short* qkv2 = h1;                                // alias (h1 dead when written)
    unsigned short* att = (unsigned short*)(ws + off + 18874368); // NHWC32 shifted, alias h1 hi
    off += 37748736;
    unsigned short* h2 = (unsigned short*)(ws + off); off += 18874368;
    unsigned short* qkv0 = (unsigned short*)(ws + off); off += 18874368;
    unsigned short* qkv1 = (unsigned short*)(ws + off); off += 18874368;
    unsigned short* qkv[3] = {qkv0, qkv1, qkv2};

    detect_kern<<<dim3(1), dim3(256), 0, stream>>>(x_raw, flag);
    prep_kern<<<dim3(256), dim3(256), 0, stream>>>(P, wb, wf, xc, flag);

    dim3 cg4(6, 96, 2), cg2(6, 192, 2), cb(256);
    for (int br = 0; br < 3; ++br) {
        conv1_mfma<<<cg4, cb, 0, stream>>>(xc, wf + OFFW1 + br * 2048,
                                           wb + OFF_B1 + br * 64, h1);
        conv2_mfma<<<cg2, cb, 0, stream>>>(h1, wf + OFFW2 + br * 18432,
                                           wb + OFF_B2 + br * 32, h2);
        conv3_mfma<<<cg4, cb, 0, stream>>>(h2, wf + OFFW3 + br * 9216,
                                           wb + OFF_B3 + br * 32, qkv[br]);
    }
    attn_kern<<<dim3(2304, 2), dim3(256), 0, stream>>>(qkv0, qkv1, qkv2, wf + OFFBT, att);
    outconv_mfma<<<cg4, cb, 0, stream>>>(att, x_raw, wf + OFFWO, wb, d_out, flag);
}

// Round 6
// 290.660 us; speedup vs baseline: 4.4246x; 1.1942x over previous
//
#include <hip/hip_runtime.h>

typedef __attribute__((ext_vector_type(8))) short bf16x8;
typedef __attribute__((ext_vector_type(4))) float f32x4;

// ---------- bf16 helpers ----------
__device__ __forceinline__ float bf2f(unsigned short u) {
    return __uint_as_float(((unsigned)u) << 16);
}
__device__ __forceinline__ unsigned short f2bf(float f) {
    unsigned u = __float_as_uint(f);
    u += 0x7fffu + ((u >> 16) & 1u);   // round-to-nearest-even
    return (unsigned short)(u >> 16);
}
__device__ __forceinline__ void unpack8(uint4 u, float* f) {
    f[0] = __uint_as_float(u.x << 16); f[1] = __uint_as_float(u.x & 0xffff0000u);
    f[2] = __uint_as_float(u.y << 16); f[3] = __uint_as_float(u.y & 0xffff0000u);
    f[4] = __uint_as_float(u.z << 16); f[5] = __uint_as_float(u.z & 0xffff0000u);
    f[6] = __uint_as_float(u.w << 16); f[7] = __uint_as_float(u.w & 0xffff0000u);
}

struct Ptrs { const unsigned short* p[22]; };

__device__ __forceinline__ float loadEl(const unsigned short* p, long i, int f32) {
    return f32 ? ((const float*)p)[i] : bf2f(p[i]);
}

// fp32 scalar region (element offsets in wb)
constexpr int OFF_B1 = 5184;
constexpr int OFF_B2 = 60672;
constexpr int OFF_B3 = 88416;
constexpr int OFF_BO = 89376;

// bf16 tables (ushort offsets in wf)
constexpr int OFFW1 = 0;        // [br][nt=4][512], n = 4*m+nt
constexpr int OFFW2 = 6144;     // [br][36 frags][512], n = 2*m+nt
constexpr int OFFW3 = 61440;    // [br][18 frags][512], n = 2*m+nt
constexpr int OFFWO = 89088;    // [9 frags][512], n = m (3 valid)
constexpr int OFFBT = 93696;    // biasT bf16 [4 cls][64 j][64 i] = 16384

constexpr int H2SZ = 9437184;   // u16 elems per branch buffer ([2][147456][32])

// ---------- input dtype detection ----------
__global__ void detect_kern(const unsigned short* x, int* flag) {
    int tid = threadIdx.x;
    int crazy = 0;
    for (int i = tid; i < 2048; i += 256) {
        unsigned short u = x[2 * i];
        int e = (u >> 7) & 0xFF;
        if (e >= 0x90) crazy++;
    }
    __shared__ int cnt;
    if (tid == 0) cnt = 0;
    __syncthreads();
    atomicAdd(&cnt, crazy);
    __syncthreads();
    if (tid == 0) *flag = (cnt > 32) ? 1 : 0;
}

// ---------- prep ----------
__global__ __launch_bounds__(256) void prep_kern(Ptrs in, float* wb, unsigned short* wf,
                                                 unsigned short* xc, const int* flagp) {
    const int f32 = *flagp;
    int tid = blockIdx.x * 256 + threadIdx.x;
    int nth = gridDim.x * 256;
    for (int i = tid; i < 192; i += nth) wb[OFF_B1 + i] = loadEl(in.p[2 + 6 * (i / 64)], i % 64, f32);
    for (int i = tid; i < 96;  i += nth) wb[OFF_B2 + i] = loadEl(in.p[4 + 6 * (i / 32)], i % 32, f32);
    for (int i = tid; i < 96;  i += nth) wb[OFF_B3 + i] = loadEl(in.p[6 + 6 * (i / 32)], i % 32, f32);
    for (int i = tid; i < 3;   i += nth) wb[OFF_BO + i] = loadEl(in.p[20], i, f32);
    // biasT bf16: pos-bias + baked shift masks, [cls][j][i] (i = query token)
    for (int i = tid; i < 16384; i += nth) {
        int cls = i >> 12, rem = i & 4095, j = rem >> 6, qi = rem & 63;
        int ih = qi >> 3, iw = qi & 7, jh = j >> 3, jw = j & 7;
        float v = loadEl(in.p[21], (jh - ih + 7) * 15 + (jw - iw + 7), f32);
        if ((cls & 1) && ((ih >= 4) != (jh >= 4))) v = -1e30f;
        if ((cls & 2) && ((iw >= 4) != (jw >= 4))) v = -1e30f;
        wf[OFFBT + i] = f2bf(v);
    }
    // wf1: conv1 (K=27 pad 32, N=64), n = 4*m + nt (lane holds adjacent ch)
    for (int i = tid; i < 3 * 2048; i += nth) {
        int br = i / 2048, r = i % 2048;
        int nt = r / 512, rr = r % 512, lane = rr >> 3, j = rr & 7;
        int k = ((lane >> 4) << 3) + j, n = 4 * (lane & 15) + nt;
        float v = 0.f;
        if (k < 27) { int tap = k / 3, cin = k - tap * 3; v = loadEl(in.p[1 + 6 * br], n * 27 + cin * 9 + tap, f32); }
        wf[OFFW1 + i] = f2bf(v);
    }
    // wf2: conv2 (K=576=tap*64+cin, N=32), n = 2*m + nt
    for (int i = tid; i < 3 * 18432; i += nth) {
        int br = i / 18432, r = i % 18432;
        int frag = r / 512, rr = r % 512, lane = rr >> 3, j = rr & 7;
        int s = frag >> 1, nt = frag & 1;
        int k = s * 32 + ((lane >> 4) << 3) + j, n = 2 * (lane & 15) + nt;
        int cin = k & 63, tap = k >> 6;
        wf[OFFW2 + i] = f2bf(loadEl(in.p[3 + 6 * br], n * 576 + cin * 9 + tap, f32));
    }
    // wf3: conv3 (K=288=tap*32+cin, N=32), n = 2*m + nt
    for (int i = tid; i < 3 * 9216; i += nth) {
        int br = i / 9216, r = i % 9216;
        int frag = r / 512, rr = r % 512, lane = rr >> 3, j = rr & 7;
        int s = frag >> 1, nt = frag & 1;
        int k = s * 32 + ((lane >> 4) << 3) + j, n = 2 * (lane & 15) + nt;
        int cin = k & 31, tap = k >> 5;
        wf[OFFW3 + i] = f2bf(loadEl(in.p[5 + 6 * br], n * 288 + cin * 9 + tap, f32));
    }
    // wfO: outconv (K=288, N=16 with 3 valid)
    for (int i = tid; i < 4608; i += nth) {
        int frag = i / 512, rr = i % 512, lane = rr >> 3, j = rr & 7;
        int k = frag * 32 + ((lane >> 4) << 3) + j, n = lane & 15;
        float v = (n < 3) ? loadEl(in.p[19], n * 288 + (k & 31) * 9 + (k >> 5), f32) : 0.f;
        wf[OFFWO + i] = f2bf(v);
    }
    // xc: NHWC with ch padded 3->4
    for (int i = tid; i < 2 * 147456 * 4; i += nth) {
        int c = i & 3, p = i >> 2;
        int b = p / 147456, hw = p % 147456;
        float v = (c < 3) ? loadEl(in.p[0], (long)(b * 3 + c) * 147456 + hw, f32) : 0.f;
        xc[i] = f2bf(v);
    }
}

// ---------- fused conv1+conv2: x -> (LDS h1) -> h2, z = br*2+b ----------
__global__ __launch_bounds__(256) void conv12_mfma(
    const unsigned short* __restrict__ xc, const unsigned short* __restrict__ wf,
    const float* __restrict__ wb, unsigned short* __restrict__ h2all) {
    __shared__ __align__(16) unsigned short sX[6][68][4];      // 3.2 KB
    __shared__ __align__(16) unsigned short sH1[264 * 72];     // 38 KB, [pixel p=r*66+c][ch]
    const int z = blockIdx.z, br = z >> 1, b = z & 1;
    const int h0 = blockIdx.y * 2, w0 = blockIdx.x * 64;
    const int tid = threadIdx.x;
    const unsigned short* wf1 = wf + OFFW1 + br * 2048;
    const unsigned short* wf2 = wf + OFFW2 + br * 18432;
    // stage x rows h0-2..h0+3, cols w0-2..w0+65
    for (int idx = tid; idx < 408; idx += 256) {
        int col = idx % 68, row = idx / 68;
        int gh = h0 + row - 2, gw = w0 + col - 2;
        uint2 v = make_uint2(0, 0);
        if ((unsigned)gh < 384u && (unsigned)gw < 384u)
            v = *(const uint2*)(xc + ((size_t)(b * 147456 + gh * 384 + gw) << 2));
        *(uint2*)(&sX[row][col][0]) = v;
    }
    __syncthreads();
    const int lane = tid & 63, wave = tid >> 6;
    const int mcol = lane & 15, q = lane >> 4;
    // ---- conv1 phase: 264 halo pixels (4 rows x 66 cols), 64 ch, into sH1 ----
    {
        float bn[4];
        bf16x8 bfr[4];
#pragma unroll
        for (int nt = 0; nt < 4; ++nt) {
            bn[nt] = wb[OFF_B1 + br * 64 + 4 * mcol + nt];
            bfr[nt] = *(const bf16x8*)(wf1 + nt * 512 + lane * 8);
        }
        for (int t = wave; t < 17; t += 4) {
            int p = t * 16 + mcol; int pc = p < 263 ? p : 263;
            int r1 = (pc * 993) >> 16, c1 = pc - r1 * 66;
            bf16x8 a;
#pragma unroll
            for (int j = 0; j < 8; ++j) {
                int k = q * 8 + j;
                int tap = k / 3, cin = k - tap * 3;
                if (tap > 8) { tap = 8; cin = 3; }
                int kh = tap / 3, kw = tap - kh * 3;
                short val = (short)sX[r1 + kh][c1 + kw][cin];
                a[j] = (k < 27) ? val : (short)0;
            }
            f32x4 acc[4];
#pragma unroll
            for (int nt = 0; nt < 4; ++nt) {
                acc[nt] = f32x4{bn[nt], bn[nt], bn[nt], bn[nt]};
                acc[nt] = __builtin_amdgcn_mfma_f32_16x16x32_bf16(a, bfr[nt], acc[nt], 0, 0, 0);
            }
#pragma unroll
            for (int r = 0; r < 4; ++r) {
                int p2 = t * 16 + q * 4 + r;
                if (p2 < 264) {
                    int r2 = (p2 * 993) >> 16, c2 = p2 - r2 * 66;
                    int gh = h0 - 1 + r2, gw = w0 - 1 + c2;
                    float scale = ((unsigned)gh < 384u && (unsigned)gw < 384u) ? 1.f : 0.f;
                    unsigned short u0 = f2bf(fmaxf(acc[0][r], 0.f) * scale);
                    unsigned short u1 = f2bf(fmaxf(acc[1][r], 0.f) * scale);
                    unsigned short u2 = f2bf(fmaxf(acc[2][r], 0.f) * scale);
                    unsigned short u3 = f2bf(fmaxf(acc[3][r], 0.f) * scale);
                    uint2 pk;
                    pk.x = (unsigned)u0 | ((unsigned)u1 << 16);
                    pk.y = (unsigned)u2 | ((unsigned)u3 << 16);
                    *(uint2*)(&sH1[p2 * 72 + 4 * mcol]) = pk;
                }
            }
        }
    }
    __syncthreads();
    // ---- conv2 phase: 2 output rows x 64 cols, 32 ch ----
    f32x4 acc0[2], acc1[2];
    {
        float b0 = wb[OFF_B2 + br * 32 + 2 * mcol], b1 = wb[OFF_B2 + br * 32 + 2 * mcol + 1];
#pragma unroll
        for (int hr = 0; hr < 2; ++hr) {
            acc0[hr] = f32x4{b0, b0, b0, b0};
            acc1[hr] = f32x4{b1, b1, b1, b1};
        }
    }
    for (int kh = 0; kh < 3; ++kh) {
        const unsigned short* wbase = wf2 + kh * 6 * 1024 + lane * 8;
#pragma unroll
        for (int u = 0; u < 6; ++u) {
            const int kw = u >> 1, ch0 = (u & 1) * 32;
            bf16x8 bf0 = *(const bf16x8*)(wbase + u * 1024);
            bf16x8 bf1 = *(const bf16x8*)(wbase + u * 1024 + 512);
#pragma unroll
            for (int hr = 0; hr < 2; ++hr) {
                int p = (kh + hr) * 66 + wave * 16 + mcol + kw;
                bf16x8 a = *(const bf16x8*)(&sH1[p * 72 + ch0 + q * 8]);
                acc0[hr] = __builtin_amdgcn_mfma_f32_16x16x32_bf16(a, bf0, acc0[hr], 0, 0, 0);
                acc1[hr] = __builtin_amdgcn_mfma_f32_16x16x32_bf16(a, bf1, acc1[hr], 0, 0, 0);
            }
        }
    }
    unsigned short* h2 = h2all + (size_t)br * H2SZ;
#pragma unroll
    for (int hr = 0; hr < 2; ++hr) {
        size_t base = (size_t)(b * 147456 + (h0 + hr) * 384 + w0 + wave * 16 + q * 4) * 32 + 2 * mcol;
#pragma unroll
        for (int r = 0; r < 4; ++r) {
            unsigned short e = f2bf(fmaxf(acc0[hr][r], 0.f));
            unsigned short o = f2bf(fmaxf(acc1[hr][r], 0.f));
            *(unsigned*)(&h2[base + (size_t)r * 32]) = (unsigned)e | ((unsigned)o << 16);
        }
    }
}

// ---------- conv3 MFMA: 32->32, QKV scatter epilogue, 4 rows/block, z = br*2+b ----------
__global__ __launch_bounds__(256) void conv3_mfma(
    const unsigned short* __restrict__ h2all, const unsigned short* __restrict__ wf,
    const float* __restrict__ wb, unsigned short* __restrict__ qkvAll) {
    __shared__ __align__(16) unsigned short sIn[6][66][40];
    const int z = blockIdx.z, br = z >> 1, b = z & 1;
    const int h0 = blockIdx.y * 4, w0 = blockIdx.x * 64;
    const int tid = threadIdx.x;
    const unsigned short* in = h2all + (size_t)br * H2SZ;
    const unsigned short* wf3 = wf + OFFW3 + br * 9216;
    unsigned short* qkv = qkvAll + (size_t)br * H2SZ;
    for (int idx = tid; idx < 1584; idx += 256) {
        int seg = idx & 3, t = idx >> 2, col = t % 66, kr = t / 66;
        int gh = h0 + kr - 1, gw = w0 + col - 1;
        uint4 v = make_uint4(0, 0, 0, 0);
        if ((unsigned)gh < 384u && (unsigned)gw < 384u)
            v = *(const uint4*)(in + ((size_t)(b * 147456 + gh * 384 + gw) << 5) + seg * 8);
        *(uint4*)(&sIn[kr][col][seg * 8]) = v;
    }
    __syncthreads();
    const int lane = tid & 63, wave = tid >> 6;
    const int mcol = lane & 15, q = lane >> 4;
    f32x4 acc0[4], acc1[4];
    {
        float b0 = wb[OFF_B3 + br * 32 + 2 * mcol], b1 = wb[OFF_B3 + br * 32 + 2 * mcol + 1];
#pragma unroll
        for (int hr = 0; hr < 4; ++hr) {
            acc0[hr] = f32x4{b0, b0, b0, b0};
            acc1[hr] = f32x4{b1, b1, b1, b1};
        }
    }
    for (int kh = 0; kh < 3; ++kh) {
        const unsigned short* wbase = wf3 + kh * 3 * 1024 + lane * 8;
#pragma unroll
        for (int u = 0; u < 3; ++u) {
            bf16x8 bf0 = *(const bf16x8*)(wbase + u * 1024);
            bf16x8 bf1 = *(const bf16x8*)(wbase + u * 1024 + 512);
#pragma unroll
            for (int hr = 0; hr < 4; ++hr) {
                bf16x8 a = *(const bf16x8*)(&sIn[kh + hr][wave * 16 + mcol + u][q * 8]);
                acc0[hr] = __builtin_amdgcn_mfma_f32_16x16x32_bf16(a, bf0, acc0[hr], 0, 0, 0);
                acc1[hr] = __builtin_amdgcn_mfma_f32_16x16x32_bf16(a, bf1, acc1[hr], 0, 0, 0);
            }
        }
    }
    const int c0 = 2 * mcol;
    const int head = c0 >> 3, d0 = c0 & 7;
#pragma unroll
    for (int hr = 0; hr < 4; ++hr) {
        int sh = h0 + hr - 4; if (sh < 0) sh += 384;
#pragma unroll
        for (int r = 0; r < 4; ++r) {
            int w = w0 + wave * 16 + q * 4 + r;
            int sw = w - 4; if (sw < 0) sw += 384;
            int win = (sh >> 3) * 48 + (sw >> 3);
            int tok = (sh & 7) * 8 + (sw & 7);
            size_t base = ((size_t)(b * 2304 + win) * 4) * 512 + tok * 8;
            unsigned short e = f2bf(acc0[hr][r]);
            unsigned short o = f2bf(acc1[hr][r]);
            *(unsigned*)(&qkv[base + (size_t)head * 512 + d0]) = (unsigned)e | ((unsigned)o << 16);
        }
    }
}

// ---------- windowed attention: branch-free no-max softmax ----------
// output att: shifted-space NHWC32 [b][384*384][32] bf16
__global__ __launch_bounds__(256) void attn_kern(
    const unsigned short* __restrict__ Q, const unsigned short* __restrict__ K,
    const unsigned short* __restrict__ V, const unsigned short* __restrict__ biasTb,
    unsigned short* __restrict__ att) {
    __shared__ float sK[4][64][8];
    __shared__ float sV[4][64][8];
    __shared__ unsigned short sB[4096];
    const int win = blockIdx.x, b = blockIdx.y;
    const int tid = threadIdx.x;
    const int head = tid >> 6, lane = tid & 63;
    const int wr = win / 48, wc = win % 48;
    const int cls = (wr == 47 ? 1 : 0) + (wc == 47 ? 2 : 0);
    {
        const uint4* gB = (const uint4*)(biasTb + cls * 4096);
        uint4* s4 = (uint4*)sB;
        s4[tid] = gB[tid];
        if (tid < 256) s4[tid + 256] = gB[tid + 256];
    }
    const size_t base = ((size_t)(b * 2304 + win) * 4 + head) * 512;
    float q[8];
    unpack8(*reinterpret_cast<const uint4*>(Q + base + lane * 8), q);
    {
        float kr[8], vr[8];
        unpack8(*reinterpret_cast<const uint4*>(K + base + lane * 8), kr);
        unpack8(*reinterpret_cast<const uint4*>(V + base + lane * 8), vr);
#pragma unroll
        for (int d = 0; d < 8; ++d) { sK[head][lane][d] = kr[d]; sV[head][lane][d] = vr[d]; }
    }
    __syncthreads();
    const float SCALE = 0.35355339059327373f;  // 8^-0.5
    float sum = 0.f;
    float o[8] = {0.f, 0.f, 0.f, 0.f, 0.f, 0.f, 0.f, 0.f};
#pragma unroll 8
    for (int j = 0; j < 64; ++j) {
        const float* kj = sK[head][j];
        float d0 = q[0] * kj[0];
#pragma unroll
        for (int d = 1; d < 8; ++d) d0 = fmaf(q[d], kj[d], d0);
        float sc = fmaf(d0, SCALE, bf2f(sB[j * 64 + lane]));
        float p = __expf(fminf(sc, 60.f));   // masked: bias -1e30 -> exp underflows to 0
        sum += p;
        const float* vj = sV[head][j];
#pragma unroll
        for (int d = 0; d < 8; ++d) o[d] = fmaf(p, vj[d], o[d]);
    }
    const float inv = 1.0f / sum;
    const int ih = lane >> 3, iw = lane & 7;
    const int px = (wr * 8 + ih) * 384 + wc * 8 + iw;
    unsigned short us[8];
#pragma unroll
    for (int d = 0; d < 8; ++d) us[d] = f2bf(o[d] * inv);
    uint4 pk;
    pk.x = (unsigned)us[0] | ((unsigned)us[1] << 16);
    pk.y = (unsigned)us[2] | ((unsigned)us[3] << 16);
    pk.z = (unsigned)us[4] | ((unsigned)us[5] << 16);
    pk.w = (unsigned)us[6] | ((unsigned)us[7] << 16);
    *(uint4*)(att + (((size_t)(b * 147456 + px)) << 5) + head * 8) = pk;
}

// ---------- out conv MFMA (shifted space, NHWC32 in) + inverse roll + residual ----------
__global__ __launch_bounds__(256) void outconv_mfma(
    const unsigned short* __restrict__ att, const unsigned short* __restrict__ x_raw,
    const unsigned short* __restrict__ wf, const float* __restrict__ wb,
    void* __restrict__ outp, const int* __restrict__ flagp) {
    __shared__ __align__(16) unsigned short sIn[6][66][40];
    const int f32 = *flagp;
    const int b = blockIdx.z, h0 = blockIdx.y * 4, w0 = blockIdx.x * 64;
    const int tid = threadIdx.x;
    for (int idx = tid; idx < 1584; idx += 256) {
        int seg = idx & 3, t = idx >> 2, col = t % 66, kr = t / 66;
        int gh = h0 + kr - 1, gw = w0 + col - 1;
        uint4 v = make_uint4(0, 0, 0, 0);
        if ((unsigned)gh < 384u && (unsigned)gw < 384u)
            v = *(const uint4*)(att + ((size_t)(b * 147456 + gh * 384 + gw) << 5) + seg * 8);
        *(uint4*)(&sIn[kr][col][seg * 8]) = v;
    }
    __syncthreads();
    const int lane = tid & 63, wave = tid >> 6;
    const int mcol = lane & 15, q = lane >> 4;
    float bn = (mcol < 3) ? wb[OFF_BO + mcol] : 0.f;
    f32x4 acc[4];
#pragma unroll
    for (int hr = 0; hr < 4; ++hr) acc[hr] = f32x4{bn, bn, bn, bn};
    for (int kh = 0; kh < 3; ++kh) {
        const unsigned short* wbase = wf + kh * 3 * 512 + lane * 8;
#pragma unroll
        for (int u = 0; u < 3; ++u) {
            bf16x8 bf = *(const bf16x8*)(wbase + u * 512);
#pragma unroll
            for (int hr = 0; hr < 4; ++hr) {
                bf16x8 a = *(const bf16x8*)(&sIn[kh + hr][wave * 16 + mcol + u][q * 8]);
                acc[hr] = __builtin_amdgcn_mfma_f32_16x16x32_bf16(a, bf, acc[hr], 0, 0, 0);
            }
        }
    }
    if (mcol < 3) {
#pragma unroll
        for (int hr = 0; hr < 4; ++hr) {
            int oh = h0 + hr + 4; if (oh >= 384) oh -= 384;
#pragma unroll
            for (int r = 0; r < 4; ++r) {
                int w = w0 + wave * 16 + q * 4 + r;
                int ow = w + 4; if (ow >= 384) ow -= 384;
                long idx = (long)(b * 3 + mcol) * 147456 + oh * 384 + ow;
                float xv = loadEl(x_raw, idx, f32);
                float o = acc[hr][r] + xv;
                if (f32) ((float*)outp)[idx] = o;
                else ((unsigned short*)outp)[idx] = f2bf(o);
            }
        }
    }
}

extern "C" void kernel_launch(void* const* d_in, const int* in_sizes, int n_in,
                              void* d_out, int out_size, void* d_ws, size_t ws_size,
                              hipStream_t stream) {
    Ptrs P;
    for (int i = 0; i < 22; ++i) P.p[i] = (const unsigned short*)d_in[i];
    const unsigned short* x_raw = (const unsigned short*)d_in[0];

    char* ws = (char*)d_ws;
    float* wb = (float*)ws;                                   // fp32 scalars (<448KB)
    int* flag = (int*)(ws + 448 * 1024);
    unsigned short* wf = (unsigned short*)(ws + 512 * 1024);  // bf16 tables (~220KB)
    unsigned short* xc = (unsigned short*)(ws + 1024 * 1024); // NHWC3(pad4), 2.36MB
    unsigned short* h2all = (unsigned short*)(ws + 3670016);  // 3 x [2][147456][32] = 56.6MB
    unsigned short* qkvAll = (unsigned short*)(ws + 3670016 + (size_t)3 * H2SZ * 2);
    unsigned short* att = h2all;                              // alias: h2 dead after conv3

    detect_kern<<<dim3(1), dim3(256), 0, stream>>>(x_raw, flag);
    prep_kern<<<dim3(256), dim3(256), 0, stream>>>(P, wb, wf, xc, flag);

    conv12_mfma<<<dim3(6, 192, 6), dim3(256), 0, stream>>>(xc, wf, wb, h2all);
    conv3_mfma<<<dim3(6, 96, 6), dim3(256), 0, stream>>>(h2all, wf, wb, qkvAll);
    attn_kern<<<dim3(2304, 2), dim3(256), 0, stream>>>(
        qkvAll, qkvAll + H2SZ, qkvAll + 2 * (size_t)H2SZ, wf + OFFBT, att);
    outconv_mfma<<<dim3(6, 96, 2), dim3(256), 0, stream>>>(att, x_raw, wf + OFFWO,
                                                           wb, d_out, flag);
}

// Round 7
// 283.627 us; speedup vs baseline: 4.5343x; 1.0248x over previous
//
#include <hip/hip_runtime.h>
#include <hip/hip_bf16.h>

typedef __attribute__((ext_vector_type(8))) short bf16x8;
typedef __attribute__((ext_vector_type(4))) float f32x4;
typedef __attribute__((ext_vector_type(2))) float f32x2;

union U8 { uint4 u; bf16x8 v; };

// ---------- bf16 helpers ----------
__device__ __forceinline__ float bf2f(unsigned short u) {
    return __uint_as_float(((unsigned)u) << 16);
}
__device__ __forceinline__ unsigned short f2bf(float f) {
    unsigned u = __float_as_uint(f);
    u += 0x7fffu + ((u >> 16) & 1u);
    return (unsigned short)(u >> 16);
}
__device__ __forceinline__ unsigned pk2bf(float a, float b) {
    __hip_bfloat162 h = __float22bfloat162_rn(make_float2(a, b));
    union { __hip_bfloat162 h; unsigned u; } cv; cv.h = h; return cv.u;
}
__device__ __forceinline__ void unpack8(uint4 u, float* f) {
    f[0] = __uint_as_float(u.x << 16); f[1] = __uint_as_float(u.x & 0xffff0000u);
    f[2] = __uint_as_float(u.y << 16); f[3] = __uint_as_float(u.y & 0xffff0000u);
    f[4] = __uint_as_float(u.z << 16); f[5] = __uint_as_float(u.z & 0xffff0000u);
    f[6] = __uint_as_float(u.w << 16); f[7] = __uint_as_float(u.w & 0xffff0000u);
}

struct Ptrs { const unsigned short* p[22]; };

__device__ __forceinline__ float loadEl(const unsigned short* p, long i, int f32) {
    return f32 ? ((const float*)p)[i] : bf2f(p[i]);
}

// fp32 scalar region (element offsets in wb)
constexpr int OFF_B1 = 5184;
constexpr int OFF_B2 = 60672;
constexpr int OFF_B3 = 88416;
constexpr int OFF_BO = 89376;

// bf16 tables (ushort offsets in wf)
constexpr int OFFW1A = 0;       // [br][nt=4][512]  taps 0..7, k=tap4+cin style
constexpr int OFFW1B = 6144;    // [br][nt=4][512]  tap 8 (k 0..3)
constexpr int OFFW2 = 12288;    // [br][36 frags][512], n = 2*m+nt
constexpr int OFFW3 = 67584;    // [br][18 frags][512], n = 2*m+nt
constexpr int OFFWO = 95232;    // [9 frags][512], n = m (3 valid)
constexpr int OFFBT = 99840;    // biasT bf16 [4 cls][64 j][64 i]

constexpr int H2SZ = 9437184;   // u16 elems per branch ([2][147456][32])

// ---------- input dtype detection ----------
__global__ void detect_kern(const unsigned short* x, int* flag) {
    int tid = threadIdx.x;
    int crazy = 0;
    for (int i = tid; i < 2048; i += 256) {
        unsigned short u = x[2 * i];
        int e = (u >> 7) & 0xFF;
        if (e >= 0x90) crazy++;
    }
    __shared__ int cnt;
    if (tid == 0) cnt = 0;
    __syncthreads();
    atomicAdd(&cnt, crazy);
    __syncthreads();
    if (tid == 0) *flag = (cnt > 32) ? 1 : 0;
}

// ---------- prep ----------
__global__ __launch_bounds__(256) void prep_kern(Ptrs in, float* wb, unsigned short* wf,
                                                 unsigned short* xc, const int* flagp) {
    const int f32 = *flagp;
    int tid = blockIdx.x * 256 + threadIdx.x;
    int nth = gridDim.x * 256;
    for (int i = tid; i < 192; i += nth) wb[OFF_B1 + i] = loadEl(in.p[2 + 6 * (i / 64)], i % 64, f32);
    for (int i = tid; i < 96;  i += nth) wb[OFF_B2 + i] = loadEl(in.p[4 + 6 * (i / 32)], i % 32, f32);
    for (int i = tid; i < 96;  i += nth) wb[OFF_B3 + i] = loadEl(in.p[6 + 6 * (i / 32)], i % 32, f32);
    for (int i = tid; i < 3;   i += nth) wb[OFF_BO + i] = loadEl(in.p[20], i, f32);
    // biasT bf16: pos-bias + baked shift masks, [cls][j][i]
    for (int i = tid; i < 16384; i += nth) {
        int cls = i >> 12, rem = i & 4095, j = rem >> 6, qi = rem & 63;
        int ih = qi >> 3, iw = qi & 7, jh = j >> 3, jw = j & 7;
        float v = loadEl(in.p[21], (jh - ih + 7) * 15 + (jw - iw + 7), f32);
        if ((cls & 1) && ((ih >= 4) != (jh >= 4))) v = -1e30f;
        if ((cls & 2) && ((iw >= 4) != (jw >= 4))) v = -1e30f;
        wf[OFFBT + i] = f2bf(v);
    }
    // wf1A: taps 0..7; lane l: n = 4*(l&15)+nt, k = (l>>4)*8+j -> tap=2q+(j>>2), cin=j&3
    for (int i = tid; i < 3 * 2048; i += nth) {
        int br = i / 2048, r = i % 2048;
        int nt = r / 512, rr = r % 512, lane = rr >> 3, j = rr & 7;
        int qq = lane >> 4, n = 4 * (lane & 15) + nt;
        int tap = 2 * qq + (j >> 2), cin = j & 3;
        float v = (cin < 3) ? loadEl(in.p[1 + 6 * br], n * 27 + cin * 9 + tap, f32) : 0.f;
        wf[OFFW1A + i] = f2bf(v);
    }
    // wf1B: tap 8 only (k = cin in 0..2, q==0)
    for (int i = tid; i < 3 * 2048; i += nth) {
        int br = i / 2048, r = i % 2048;
        int nt = r / 512, rr = r % 512, lane = rr >> 3, j = rr & 7;
        int qq = lane >> 4, n = 4 * (lane & 15) + nt;
        float v = (qq == 0 && j < 3) ? loadEl(in.p[1 + 6 * br], n * 27 + j * 9 + 8, f32) : 0.f;
        wf[OFFW1B + i] = f2bf(v);
    }
    // wf2: conv2 (K=576=tap*64+cin, N=32), n = 2*m+nt
    for (int i = tid; i < 3 * 18432; i += nth) {
        int br = i / 18432, r = i % 18432;
        int frag = r / 512, rr = r % 512, lane = rr >> 3, j = rr & 7;
        int s = frag >> 1, nt = frag & 1;
        int k = s * 32 + ((lane >> 4) << 3) + j, n = 2 * (lane & 15) + nt;
        int cin = k & 63, tap = k >> 6;
        wf[OFFW2 + i] = f2bf(loadEl(in.p[3 + 6 * br], n * 576 + cin * 9 + tap, f32));
    }
    // wf3: conv3 (K=288=tap*32+cin, N=32), n = 2*m+nt
    for (int i = tid; i < 3 * 9216; i += nth) {
        int br = i / 9216, r = i % 9216;
        int frag = r / 512, rr = r % 512, lane = rr >> 3, j = rr & 7;
        int s = frag >> 1, nt = frag & 1;
        int k = s * 32 + ((lane >> 4) << 3) + j, n = 2 * (lane & 15) + nt;
        int cin = k & 31, tap = k >> 5;
        wf[OFFW3 + i] = f2bf(loadEl(in.p[5 + 6 * br], n * 288 + cin * 9 + tap, f32));
    }
    // wfO: outconv (K=288, N=16 with 3 valid)
    for (int i = tid; i < 4608; i += nth) {
        int frag = i / 512, rr = i % 512, lane = rr >> 3, j = rr & 7;
        int k = frag * 32 + ((lane >> 4) << 3) + j, n = lane & 15;
        float v = (n < 3) ? loadEl(in.p[19], n * 288 + (k & 31) * 9 + (k >> 5), f32) : 0.f;
        wf[OFFWO + i] = f2bf(v);
    }
    // xc: NHWC with ch padded 3->4
    for (int i = tid; i < 2 * 147456 * 4; i += nth) {
        int c = i & 3, p = i >> 2;
        int b = p / 147456, hw = p % 147456;
        float v = (c < 3) ? loadEl(in.p[0], (long)(b * 3 + c) * 147456 + hw, f32) : 0.f;
        xc[i] = f2bf(v);
    }
}

// ---------- fused conv1+conv2: x -> (LDS h1) -> h2, z = br*2+b ----------
__global__ __launch_bounds__(256) void conv12_mfma(
    const unsigned short* __restrict__ xc, const unsigned short* __restrict__ wf,
    const float* __restrict__ wb, unsigned short* __restrict__ h2all) {
    __shared__ __align__(16) unsigned short sX[6][68][4];      // 3.2 KB
    __shared__ __align__(16) unsigned short sH1[264 * 76];     // 40.1 KB, stride 76
    const int z = blockIdx.z, br = z >> 1, b = z & 1;
    const int h0 = blockIdx.y * 2, w0 = blockIdx.x * 64;
    const int tid = threadIdx.x;
    const unsigned short* wf1a = wf + OFFW1A + br * 2048;
    const unsigned short* wf1b = wf + OFFW1B + br * 2048;
    const unsigned short* wf2 = wf + OFFW2 + br * 18432;
    for (int idx = tid; idx < 408; idx += 256) {
        int col = idx % 68, row = idx / 68;
        int gh = h0 + row - 2, gw = w0 + col - 2;
        uint2 v = make_uint2(0, 0);
        if ((unsigned)gh < 384u && (unsigned)gw < 384u)
            v = *(const uint2*)(xc + ((size_t)(b * 147456 + gh * 384 + gw) << 2));
        *(uint2*)(&sX[row][col][0]) = v;
    }
    __syncthreads();
    const int lane = tid & 63, wave = tid >> 6;
    const int mcol = lane & 15, q = lane >> 4;
    // per-lane tap geometry for MFMA-A (taps 2q, 2q+1)
    const int tA0 = 2 * q, tA1 = 2 * q + 1;
    const int khA0 = (tA0 * 11) >> 5, kwA0 = tA0 - khA0 * 3;
    const int khA1 = (tA1 * 11) >> 5, kwA1 = tA1 - khA1 * 3;
    // ---- conv1 phase ----
    {
        float bn[4];
        bf16x8 wA[4], wB[4];
#pragma unroll
        for (int nt = 0; nt < 4; ++nt) {
            bn[nt] = wb[OFF_B1 + br * 64 + 4 * mcol + nt];
            wA[nt] = *(const bf16x8*)(wf1a + nt * 512 + lane * 8);
            wB[nt] = *(const bf16x8*)(wf1b + nt * 512 + lane * 8);
        }
        for (int t = wave; t < 17; t += 4) {
            int p = t * 16 + mcol; int pcl = p < 263 ? p : 263;
            int r1 = (pcl * 993) >> 16, c1 = pcl - r1 * 66;
            uint2 pa = *(const uint2*)&sX[r1 + khA0][c1 + kwA0][0];
            uint2 pb = *(const uint2*)&sX[r1 + khA1][c1 + kwA1][0];
            uint2 pc2 = *(const uint2*)&sX[r1 + 2][c1 + 2][0];
            U8 ua; ua.u = make_uint4(pa.x, pa.y, pb.x, pb.y);
            U8 ub; ub.u = make_uint4(pc2.x, pc2.y, 0u, 0u);
            f32x4 acc[4];
#pragma unroll
            for (int nt = 0; nt < 4; ++nt) {
                acc[nt] = f32x4{bn[nt], bn[nt], bn[nt], bn[nt]};
                acc[nt] = __builtin_amdgcn_mfma_f32_16x16x32_bf16(ua.v, wA[nt], acc[nt], 0, 0, 0);
                acc[nt] = __builtin_amdgcn_mfma_f32_16x16x32_bf16(ub.v, wB[nt], acc[nt], 0, 0, 0);
            }
#pragma unroll
            for (int r = 0; r < 4; ++r) {
                int p2 = t * 16 + q * 4 + r;
                if (p2 < 264) {
                    int r2 = (p2 * 993) >> 16, c2 = p2 - r2 * 66;
                    unsigned lo = pk2bf(fmaxf(acc[0][r], 0.f), fmaxf(acc[1][r], 0.f));
                    unsigned hi = pk2bf(fmaxf(acc[2][r], 0.f), fmaxf(acc[3][r], 0.f));
                    bool inb = ((unsigned)(h0 - 1 + r2) < 384u) && ((unsigned)(w0 - 1 + c2) < 384u);
                    if (!inb) { lo = 0u; hi = 0u; }
                    *(uint2*)(&sH1[p2 * 76 + 4 * mcol]) = make_uint2(lo, hi);
                }
            }
        }
    }
    __syncthreads();
    // ---- conv2 phase ----
    f32x4 acc0[2], acc1[2];
    {
        float b0 = wb[OFF_B2 + br * 32 + 2 * mcol], b1 = wb[OFF_B2 + br * 32 + 2 * mcol + 1];
#pragma unroll
        for (int hr = 0; hr < 2; ++hr) {
            acc0[hr] = f32x4{b0, b0, b0, b0};
            acc1[hr] = f32x4{b1, b1, b1, b1};
        }
    }
    for (int kh = 0; kh < 3; ++kh) {
        const unsigned short* wbase = wf2 + kh * 6 * 1024 + lane * 8;
#pragma unroll
        for (int u = 0; u < 6; ++u) {
            const int kw = u >> 1, ch0 = (u & 1) * 32;
            bf16x8 bf0 = *(const bf16x8*)(wbase + u * 1024);
            bf16x8 bf1 = *(const bf16x8*)(wbase + u * 1024 + 512);
#pragma unroll
            for (int hr = 0; hr < 2; ++hr) {
                int p = (kh + hr) * 66 + wave * 16 + mcol + kw;
                const unsigned short* ap = &sH1[p * 76 + ch0 + q * 8];
                uint2 lo = *(const uint2*)ap;
                uint2 hi = *(const uint2*)(ap + 4);
                U8 ua; ua.u = make_uint4(lo.x, lo.y, hi.x, hi.y);
                acc0[hr] = __builtin_amdgcn_mfma_f32_16x16x32_bf16(ua.v, bf0, acc0[hr], 0, 0, 0);
                acc1[hr] = __builtin_amdgcn_mfma_f32_16x16x32_bf16(ua.v, bf1, acc1[hr], 0, 0, 0);
            }
        }
    }
    unsigned short* h2 = h2all + (size_t)br * H2SZ;
#pragma unroll
    for (int hr = 0; hr < 2; ++hr) {
        size_t base = (size_t)(b * 147456 + (h0 + hr) * 384 + w0 + wave * 16 + q * 4) * 32 + 2 * mcol;
#pragma unroll
        for (int r = 0; r < 4; ++r)
            *(unsigned*)(&h2[base + (size_t)r * 32]) =
                pk2bf(fmaxf(acc0[hr][r], 0.f), fmaxf(acc1[hr][r], 0.f));
    }
}

// ---------- conv3: 32->32, writes qkv [b][win][tok][32] (coalesced) ----------
__global__ __launch_bounds__(256) void conv3_mfma(
    const unsigned short* __restrict__ h2all, const unsigned short* __restrict__ wf,
    const float* __restrict__ wb, unsigned short* __restrict__ qkvAll) {
    __shared__ __align__(16) unsigned short sIn[6][66][40];
    const int z = blockIdx.z, br = z >> 1, b = z & 1;
    const int h0 = blockIdx.y * 4, w0 = blockIdx.x * 64;
    const int tid = threadIdx.x;
    const unsigned short* in = h2all + (size_t)br * H2SZ;
    const unsigned short* wf3 = wf + OFFW3 + br * 9216;
    unsigned short* qkv = qkvAll + (size_t)br * H2SZ;
    for (int idx = tid; idx < 1584; idx += 256) {
        int seg = idx & 3, t = idx >> 2, col = t % 66, kr = t / 66;
        int gh = h0 + kr - 1, gw = w0 + col - 1;
        uint4 v = make_uint4(0, 0, 0, 0);
        if ((unsigned)gh < 384u && (unsigned)gw < 384u)
            v = *(const uint4*)(in + ((size_t)(b * 147456 + gh * 384 + gw) << 5) + seg * 8);
        *(uint4*)(&sIn[kr][col][seg * 8]) = v;
    }
    __syncthreads();
    const int lane = tid & 63, wave = tid >> 6;
    const int mcol = lane & 15, q = lane >> 4;
    f32x4 acc0[4], acc1[4];
    {
        float b0 = wb[OFF_B3 + br * 32 + 2 * mcol], b1 = wb[OFF_B3 + br * 32 + 2 * mcol + 1];
#pragma unroll
        for (int hr = 0; hr < 4; ++hr) {
            acc0[hr] = f32x4{b0, b0, b0, b0};
            acc1[hr] = f32x4{b1, b1, b1, b1};
        }
    }
    for (int kh = 0; kh < 3; ++kh) {
        const unsigned short* wbase = wf3 + kh * 3 * 1024 + lane * 8;
#pragma unroll
        for (int u = 0; u < 3; ++u) {
            bf16x8 bf0 = *(const bf16x8*)(wbase + u * 1024);
            bf16x8 bf1 = *(const bf16x8*)(wbase + u * 1024 + 512);
#pragma unroll
            for (int hr = 0; hr < 4; ++hr) {
                bf16x8 a = *(const bf16x8*)(&sIn[kh + hr][wave * 16 + mcol + u][q * 8]);
                acc0[hr] = __builtin_amdgcn_mfma_f32_16x16x32_bf16(a, bf0, acc0[hr], 0, 0, 0);
                acc1[hr] = __builtin_amdgcn_mfma_f32_16x16x32_bf16(a, bf1, acc1[hr], 0, 0, 0);
            }
        }
    }
#pragma unroll
    for (int hr = 0; hr < 4; ++hr) {
        int sh = h0 + hr - 4; if (sh < 0) sh += 384;
#pragma unroll
        for (int r = 0; r < 4; ++r) {
            int w = w0 + wave * 16 + q * 4 + r;
            int sw = w - 4; if (sw < 0) sw += 384;
            int win = (sh >> 3) * 48 + (sw >> 3);
            int tok = (sh & 7) * 8 + (sw & 7);
            size_t tb = ((size_t)(b * 2304 + win) * 64 + tok) * 32;
            *(unsigned*)(&qkv[tb + 2 * mcol]) = pk2bf(acc0[hr][r], acc1[hr][r]);
        }
    }
}

// ---------- windowed attention: branch-free softmax, packed f32 math ----------
// qkv layout: [b][win][tok][32]; output att: shifted-space NHWC32
__global__ __launch_bounds__(256) void attn_kern(
    const unsigned short* __restrict__ Q, const unsigned short* __restrict__ K,
    const unsigned short* __restrict__ V, const unsigned short* __restrict__ biasTb,
    unsigned short* __restrict__ att) {
    __shared__ f32x2 sK[4][64][4];
    __shared__ f32x2 sV[4][64][4];
    __shared__ unsigned short sB[4096];
    const int win = blockIdx.x, b = blockIdx.y;
    const int tid = threadIdx.x;
    const int head = tid >> 6, lane = tid & 63;
    const int wr = win / 48, wc = win % 48;
    const int cls = (wr == 47 ? 1 : 0) + (wc == 47 ? 2 : 0);
    {
        const uint4* gB = (const uint4*)(biasTb + cls * 4096);
        uint4* s4 = (uint4*)sB;
        s4[tid] = gB[tid];
        if (tid < 256) s4[tid + 256] = gB[tid + 256];
    }
    const size_t tb = ((size_t)(b * 2304 + win) * 64 + lane) * 32 + head * 8;
    float qf[8];
    unpack8(*reinterpret_cast<const uint4*>(Q + tb), qf);
    f32x2 q2[4];
#pragma unroll
    for (int i = 0; i < 4; ++i) q2[i] = f32x2{qf[2 * i], qf[2 * i + 1]};
    {
        float kr[8], vr[8];
        unpack8(*reinterpret_cast<const uint4*>(K + tb), kr);
        unpack8(*reinterpret_cast<const uint4*>(V + tb), vr);
#pragma unroll
        for (int i = 0; i < 4; ++i) {
            sK[head][lane][i] = f32x2{kr[2 * i], kr[2 * i + 1]};
            sV[head][lane][i] = f32x2{vr[2 * i], vr[2 * i + 1]};
        }
    }
    __syncthreads();
    const float SCALE = 0.35355339059327373f;
    float sum = 0.f;
    f32x2 o2[4] = {f32x2{0.f, 0.f}, f32x2{0.f, 0.f}, f32x2{0.f, 0.f}, f32x2{0.f, 0.f}};
#pragma unroll 8
    for (int j = 0; j < 64; ++j) {
        f32x2 k0 = sK[head][j][0], k1 = sK[head][j][1];
        f32x2 k2 = sK[head][j][2], k3 = sK[head][j][3];
        f32x2 a2 = q2[0] * k0;
        a2 = __builtin_elementwise_fma(q2[1], k1, a2);
        a2 = __builtin_elementwise_fma(q2[2], k2, a2);
        a2 = __builtin_elementwise_fma(q2[3], k3, a2);
        float d0 = a2[0] + a2[1];
        float sc = fmaf(d0, SCALE, bf2f(sB[j * 64 + lane]));
        float p = __expf(fminf(sc, 60.f));
        sum += p;
        f32x2 pp = f32x2{p, p};
#pragma unroll
        for (int i = 0; i < 4; ++i)
            o2[i] = __builtin_elementwise_fma(pp, sV[head][j][i], o2[i]);
    }
    const float inv = 1.0f / sum;
    const int ih = lane >> 3, iw = lane & 7;
    const int px = (wr * 8 + ih) * 384 + wc * 8 + iw;
    uint4 pk;
    pk.x = pk2bf(o2[0][0] * inv, o2[0][1] * inv);
    pk.y = pk2bf(o2[1][0] * inv, o2[1][1] * inv);
    pk.z = pk2bf(o2[2][0] * inv, o2[2][1] * inv);
    pk.w = pk2bf(o2[3][0] * inv, o2[3][1] * inv);
    *(uint4*)(att + (((size_t)(b * 147456 + px)) << 5) + head * 8) = pk;
}

// ---------- out conv MFMA (shifted space, NHWC32 in) + inverse roll + residual ----------
__global__ __launch_bounds__(256) void outconv_mfma(
    const unsigned short* __restrict__ att, const unsigned short* __restrict__ x_raw,
    const unsigned short* __restrict__ wf, const float* __restrict__ wb,
    void* __restrict__ outp, const int* __restrict__ flagp) {
    __shared__ __align__(16) unsigned short sIn[6][66][40];
    const int f32 = *flagp;
    const int b = blockIdx.z, h0 = blockIdx.y * 4, w0 = blockIdx.x * 64;
    const int tid = threadIdx.x;
    for (int idx = tid; idx < 1584; idx += 256) {
        int seg = idx & 3, t = idx >> 2, col = t % 66, kr = t / 66;
        int gh = h0 + kr - 1, gw = w0 + col - 1;
        uint4 v = make_uint4(0, 0, 0, 0);
        if ((unsigned)gh < 384u && (unsigned)gw < 384u)
            v = *(const uint4*)(att + ((size_t)(b * 147456 + gh * 384 + gw) << 5) + seg * 8);
        *(uint4*)(&sIn[kr][col][seg * 8]) = v;
    }
    __syncthreads();
    const int lane = tid & 63, wave = tid >> 6;
    const int mcol = lane & 15, q = lane >> 4;
    float bn = (mcol < 3) ? wb[OFF_BO + mcol] : 0.f;
    f32x4 acc[4];
#pragma unroll
    for (int hr = 0; hr < 4; ++hr) acc[hr] = f32x4{bn, bn, bn, bn};
    for (int kh = 0; kh < 3; ++kh) {
        const unsigned short* wbase = wf + kh * 3 * 512 + lane * 8;
#pragma unroll
        for (int u = 0; u < 3; ++u) {
            bf16x8 bf = *(const bf16x8*)(wbase + u * 512);
#pragma unroll
            for (int hr = 0; hr < 4; ++hr) {
                bf16x8 a = *(const bf16x8*)(&sIn[kh + hr][wave * 16 + mcol + u][q * 8]);
                acc[hr] = __builtin_amdgcn_mfma_f32_16x16x32_bf16(a, bf, acc[hr], 0, 0, 0);
            }
        }
    }
    if (mcol < 3) {
#pragma unroll
        for (int hr = 0; hr < 4; ++hr) {
            int oh = h0 + hr + 4; if (oh >= 384) oh -= 384;
#pragma unroll
            for (int r = 0; r < 4; ++r) {
                int w = w0 + wave * 16 + q * 4 + r;
                int ow = w + 4; if (ow >= 384) ow -= 384;
                long idx = (long)(b * 3 + mcol) * 147456 + oh * 384 + ow;
                float xv = loadEl(x_raw, idx, f32);
                float o = acc[hr][r] + xv;
                if (f32) ((float*)outp)[idx] = o;
                else ((unsigned short*)outp)[idx] = f2bf(o);
            }
        }
    }
}

extern "C" void kernel_launch(void* const* d_in, const int* in_sizes, int n_in,
                              void* d_out, int out_size, void* d_ws, size_t ws_size,
                              hipStream_t stream) {
    Ptrs P;
    for (int i = 0; i < 22; ++i) P.p[i] = (const unsigned short*)d_in[i];
    const unsigned short* x_raw = (const unsigned short*)d_in[0];

    char* ws = (char*)d_ws;
    float* wb = (float*)ws;
    int* flag = (int*)(ws + 448 * 1024);
    unsigned short* wf = (unsigned short*)(ws + 512 * 1024);  // bf16 tables (~232KB)
    unsigned short* xc = (unsigned short*)(ws + 1024 * 1024);
    unsigned short* h2all = (unsigned short*)(ws + 3670016);  // 3 x [2][147456][32]
    unsigned short* qkvAll = (unsigned short*)(ws + 3670016 + (size_t)3 * H2SZ * 2);
    unsigned short* att = h2all;                              // alias: h2 dead after conv3

    detect_kern<<<dim3(1), dim3(256), 0, stream>>>(x_raw, flag);
    prep_kern<<<dim3(256), dim3(256), 0, stream>>>(P, wb, wf, xc, flag);

    conv12_mfma<<<dim3(6, 192, 6), dim3(256), 0, stream>>>(xc, wf, wb, h2all);
    conv3_mfma<<<dim3(6, 96, 6), dim3(256), 0, stream>>>(h2all, wf, wb, qkvAll);
    attn_kern<<<dim3(2304, 2), dim3(256), 0, stream>>>(
        qkvAll, qkvAll + H2SZ, qkvAll + 2 * (size_t)H2SZ, wf + OFFBT, att);
    outconv_mfma<<<dim3(6, 96, 2), dim3(256), 0, stream>>>(att, x_raw, wf + OFFWO,
                                                           wb, d_out, flag);
}